// Round 3
// baseline (315.806 us; speedup 1.0000x reference)
//
#include <hip/hip_runtime.h>
#include <hip/hip_bf16.h>
#include <cstdint>
#include <cstddef>

typedef __bf16 bf16;
typedef __bf16 bf16x8 __attribute__((ext_vector_type(8)));
typedef float  f32x4  __attribute__((ext_vector_type(4)));

// ---------------------------------------------------------------------------
// Dtype detection: if d_in[0] is fp32, the low 16 bits of each word are
// mantissa garbage -> decoded as bf16, ~half have |x| >= 2^7. If it's real
// bf16 N(0,1) data, none do. Writes flag: 1 = fp32 inputs, 0 = bf16 inputs.
// ---------------------------------------------------------------------------
__global__ void detect_dtype(const unsigned int* __restrict__ w, int* __restrict__ flag) {
  const int t = threadIdx.x;           // 64 threads
  int weird = 0;
#pragma unroll
  for (int c = 0; c < 2; ++c) {
    const unsigned int lo = w[c * 64 + t] & 0xffffu;
    const unsigned int ex = (lo >> 7) & 0xffu;
    if (ex >= 134u) ++weird;           // |bf16| >= 128 (or inf/nan)
  }
  const unsigned long long m1 = __ballot(weird >= 1);
  const unsigned long long m2 = __ballot(weird == 2);
  if (t == 0) *flag = (__popcll(m1) + __popcll(m2) >= 8) ? 1 : 0;
}

// Convert input (fp32 or bf16, per flag) to bf16.
__global__ __launch_bounds__(256) void convert_to_bf16(
    const void* __restrict__ src, bf16* __restrict__ dst, int n,
    const int* __restrict__ flag) {
  const int i = blockIdx.x * 256 + threadIdx.x;
  if (i >= n) return;
  const float v = (*flag) ? ((const float*)src)[i] : (float)((const bf16*)src)[i];
  dst[i] = (bf16)v;
}

// Write output in the dtype matching the inputs.
__global__ __launch_bounds__(256) void write_out(
    const bf16* __restrict__ src, void* __restrict__ out, int n,
    const int* __restrict__ flag) {
  const int i = blockIdx.x * 256 + threadIdx.x;
  if (i >= n) return;
  if (*flag) ((float*)out)[i] = (float)src[i];
  else       ((bf16*)out)[i]  = src[i];
}

// ---------------------------------------------------------------------------
// GEMM:  C[M,N] = A[M,K] * B[N,K]^T   (both operands K-major, bf16, fp32 acc)
// 128x128 tile, BK=32, 4 waves (2x2 of 64x64), 16x16x32 bf16 MFMA.
// ---------------------------------------------------------------------------
__global__ __launch_bounds__(256) void gemm_bt(
    const bf16* __restrict__ A, const bf16* __restrict__ B,
    bf16* __restrict__ C, int M, int N, int K)
{
  __shared__ __align__(16) bf16 As[128 * 32];
  __shared__ __align__(16) bf16 Bs[128 * 32];
  const int tid  = threadIdx.x;
  const int wave = tid >> 6;
  const int lane = tid & 63;
  const int l15  = lane & 15;
  const int l4   = lane >> 4;
  const int m0 = blockIdx.y * 128;
  const int n0 = blockIdx.x * 128;
  const int wm = (wave >> 1) * 64;
  const int wn = (wave & 1) * 64;

  f32x4 acc[4][4] = {};

  const int srow = wave * 16 + (lane >> 2);   // + c*64
  const int sk   = (lane & 3) * 8;
  const bf16* Ab = A + (size_t)(m0 + srow) * K + sk;
  const bf16* Bb = B + (size_t)(n0 + srow) * K + sk;
  const int ldsoff = wave * 512 + lane * 8;   // == srow*32 + sk (linear)

  for (int kt = 0; kt < K; kt += 32) {
    const bf16x8 a0 = *(const bf16x8*)(Ab + kt);
    const bf16x8 a1 = *(const bf16x8*)(Ab + (size_t)64 * K + kt);
    const bf16x8 b0 = *(const bf16x8*)(Bb + kt);
    const bf16x8 b1 = *(const bf16x8*)(Bb + (size_t)64 * K + kt);
    *(bf16x8*)(As + ldsoff)        = a0;
    *(bf16x8*)(As + 2048 + ldsoff) = a1;
    *(bf16x8*)(Bs + ldsoff)        = b0;
    *(bf16x8*)(Bs + 2048 + ldsoff) = b1;
    __syncthreads();
    bf16x8 af[4], bfr[4];
#pragma unroll
    for (int i = 0; i < 4; ++i)
      af[i] = *(const bf16x8*)(As + (wm + i * 16 + l15) * 32 + l4 * 8);
#pragma unroll
    for (int j = 0; j < 4; ++j)
      bfr[j] = *(const bf16x8*)(Bs + (wn + j * 16 + l15) * 32 + l4 * 8);
#pragma unroll
    for (int i = 0; i < 4; ++i)
#pragma unroll
      for (int j = 0; j < 4; ++j)
        acc[i][j] = __builtin_amdgcn_mfma_f32_16x16x32_bf16(af[i], bfr[j], acc[i][j], 0, 0, 0);
    __syncthreads();
  }

  // C/D layout: col = lane&15, row = (lane>>4)*4 + reg  [m89]
#pragma unroll
  for (int i = 0; i < 4; ++i)
#pragma unroll
    for (int j = 0; j < 4; ++j) {
      bf16* cp = C + (size_t)(m0 + wm + i * 16 + l4 * 4) * N + (n0 + wn + j * 16 + l15);
#pragma unroll
      for (int r = 0; r < 4; ++r)
        cp[(size_t)r * N] = (bf16)acc[i][j][r];
    }
}

// ---------------------------------------------------------------------------
// RoPE (neox, full rotary dim) + relayout.
//   qkv row-major [2048, 3072] ->
//   Q [B,NH,S,64]  (scaled by 1/8), K [B,NKV,S,64], Vt [B,NKV,64,S]
// ---------------------------------------------------------------------------
__global__ __launch_bounds__(256) void rope_relayout(
    const bf16* __restrict__ qkv, const int* __restrict__ pos,
    bf16* __restrict__ Q, bf16* __restrict__ K, bf16* __restrict__ V)
{
  const int idx = blockIdx.x * 256 + threadIdx.x;     // 0 .. 2048*3072-1
  const int row = idx / 3072;
  const int col = idx - row * 3072;
  const int b = row >> 10, s = row & 1023;
  const float x = (float)qkv[idx];

  if (col >= 2560) {  // V: no rope, transpose to [d][s]
    const int h = (col - 2560) >> 6, d = (col - 2560) & 63;
    V[(((size_t)(b * 8 + h)) * 64 + d) * 1024 + s] = (bf16)x;
    return;
  }
  const float xp = (float)qkv[row * 3072 + (col ^ 32)];   // partner half
  const int hd = (col < 2048) ? col : col - 2048;
  const int d = hd & 63;
  const int fi = d & 31;
  // inv_freq = theta^(-fi/32), ln(500000)/32 = 0.41007385554
  const float ang = (float)pos[row] * __expf((float)fi * -0.41007385554f);
  float sn, cs;
  sincosf(ang, &sn, &cs);
  const float v = (d < 32) ? (x * cs - xp * sn) : (x * cs + xp * sn);
  if (col < 2048) {
    const int h = col >> 6;
    Q[(((size_t)(b * 32 + h)) * 1024 + s) * 64 + d] = (bf16)(v * 0.125f);  // fold SCALE
  } else {
    const int h = hd >> 6;
    K[(((size_t)(b * 8 + h)) * 1024 + s) * 64 + d] = (bf16)v;
  }
}

// ---------------------------------------------------------------------------
// Flash attention, causal GQA. Block = (qt, b*32+h), 256 thr (4 waves x 32 q-rows).
// Q-tile 128, K-tile 64. Online softmax. O -> attn_out [B*S, 2048] bf16.
// ---------------------------------------------------------------------------
__global__ __launch_bounds__(256) void attn_kernel(
    const bf16* __restrict__ Q, const bf16* __restrict__ K,
    const bf16* __restrict__ Vt, bf16* __restrict__ O)
{
  __shared__ __align__(16) bf16 Ks[2 * 64 * 32];   // [dchunk][key][32]
  __shared__ __align__(16) bf16 Vs[2 * 64 * 32];   // [kchunk][d][32]
  __shared__ __align__(16) bf16 Ps[128 * 64];      // swizzled P; also Q staging

  const int tid = threadIdx.x, wave = tid >> 6, lane = tid & 63;
  const int l15 = lane & 15, l4 = lane >> 4;
  const int qt = blockIdx.x, bh = blockIdx.y;
  const int b = bh >> 5, h = bh & 31, kvh = h >> 2;
  const int q0 = qt * 128;
  const bf16* Qb = Q + (((size_t)(b * 32 + h)) * 1024 + q0) * 64;
  const bf16* Kb = K + ((size_t)(b * 8 + kvh)) * 1024 * 64;
  const bf16* Vb = Vt + ((size_t)(b * 8 + kvh)) * 64 * 1024;

  // ---- stage Q tile [dchunk:2][row:128][32] into Ps, then pull frags to regs
#pragma unroll
  for (int c = 0; c < 4; ++c) {
    const int e = c * 2048 + tid * 8;
    const int cd = e >> 12;
    const int row = (e & 4095) >> 5;
    const int dk = cd * 32 + (e & 31);
    const bf16x8 qv = *(const bf16x8*)(Qb + row * 64 + dk);
    *(bf16x8*)(Ps + e) = qv;
  }
  __syncthreads();
  bf16x8 aq[2][2];
#pragma unroll
  for (int i = 0; i < 2; ++i)
#pragma unroll
    for (int s = 0; s < 2; ++s)
      aq[i][s] = *(const bf16x8*)(Ps + s * 4096 + (wave * 32 + i * 16 + l15) * 32 + l4 * 8);
  __syncthreads();

  float m_s[2][4], l_s[2][4];
  f32x4 o_acc[2][4] = {};
#pragma unroll
  for (int i = 0; i < 2; ++i)
#pragma unroll
    for (int r = 0; r < 4; ++r) { m_s[i][r] = -3.0e4f; l_s[i][r] = 0.f; }

  const int nkt = 2 * qt + 2;   // causal: keys 0 .. q0+127
  for (int kt = 0; kt < nkt; ++kt) {
    const int k0 = kt * 64;
#pragma unroll
    for (int c = 0; c < 2; ++c) {
      const int e = c * 2048 + tid * 8;
      const int cd = e >> 11;
      const int rr = (e & 2047) >> 5;
      const int dk = cd * 32 + (e & 31);
      const bf16x8 kv = *(const bf16x8*)(Kb + (size_t)(k0 + rr) * 64 + dk);
      const bf16x8 vv = *(const bf16x8*)(Vb + (size_t)rr * 1024 + k0 + dk);
      *(bf16x8*)(Ks + e) = kv;
      *(bf16x8*)(Vs + e) = vv;
    }
    __syncthreads();

    // ---- S = Q K^T (scale pre-folded into Q)
    f32x4 sc[2][4] = {};
#pragma unroll
    for (int j = 0; j < 4; ++j) {
      const bf16x8 bk0 = *(const bf16x8*)(Ks + (j * 16 + l15) * 32 + l4 * 8);
      const bf16x8 bk1 = *(const bf16x8*)(Ks + 2048 + (j * 16 + l15) * 32 + l4 * 8);
#pragma unroll
      for (int i = 0; i < 2; ++i) {
        sc[i][j] = __builtin_amdgcn_mfma_f32_16x16x32_bf16(aq[i][0], bk0, sc[i][j], 0, 0, 0);
        sc[i][j] = __builtin_amdgcn_mfma_f32_16x16x32_bf16(aq[i][1], bk1, sc[i][j], 0, 0, 0);
      }
    }

    // ---- mask + online softmax; write P (bf16) to swizzled LDS
#pragma unroll
    for (int i = 0; i < 2; ++i) {
#pragma unroll
      for (int r = 0; r < 4; ++r) {
        const int rr = wave * 32 + i * 16 + l4 * 4 + r;
        const int rg = q0 + rr;
        float mx = -3.0e4f;
#pragma unroll
        for (int j = 0; j < 4; ++j) {
          float v = sc[i][j][r];
          if (k0 + j * 16 + l15 > rg) v = -3.0e4f;
          sc[i][j][r] = v;
          mx = fmaxf(mx, v);
        }
#pragma unroll
        for (int off = 1; off < 16; off <<= 1) mx = fmaxf(mx, __shfl_xor(mx, off));
        const float mnew = fmaxf(m_s[i][r], mx);
        const float alpha = __expf(m_s[i][r] - mnew);
        m_s[i][r] = mnew;
        float rs = 0.f;
        const int sw = rr & 7;
#pragma unroll
        for (int j = 0; j < 4; ++j) {
          const float pv = __expf(sc[i][j][r] - mnew);
          rs += pv;
          const int k = j * 16 + l15;
          Ps[rr * 64 + (((k >> 3) ^ sw) << 3) + (k & 7)] = (bf16)pv;
        }
#pragma unroll
        for (int off = 1; off < 16; off <<= 1) rs += __shfl_xor(rs, off);
        l_s[i][r] = l_s[i][r] * alpha + rs;
#pragma unroll
        for (int jd = 0; jd < 4; ++jd) o_acc[i][jd][r] *= alpha;
      }
    }
    __syncthreads();

    // ---- O += P V   (A-frags from swizzled Ps, B-frags from Vs)
#pragma unroll
    for (int ks = 0; ks < 2; ++ks) {
      bf16x8 ap[2];
#pragma unroll
      for (int i = 0; i < 2; ++i) {
        const int rr = wave * 32 + i * 16 + l15;
        const int g = (ks * 4 + l4) ^ (rr & 7);
        ap[i] = *(const bf16x8*)(Ps + rr * 64 + g * 8);
      }
#pragma unroll
      for (int jd = 0; jd < 4; ++jd) {
        const bf16x8 bv = *(const bf16x8*)(Vs + ks * 2048 + (jd * 16 + l15) * 32 + l4 * 8);
#pragma unroll
        for (int i = 0; i < 2; ++i)
          o_acc[i][jd] = __builtin_amdgcn_mfma_f32_16x16x32_bf16(ap[i], bv, o_acc[i][jd], 0, 0, 0);
      }
    }
    __syncthreads();
  }

  // ---- epilogue: O /= l, write [B*S, NH*64]
#pragma unroll
  for (int i = 0; i < 2; ++i)
#pragma unroll
    for (int r = 0; r < 4; ++r) {
      const int srow = q0 + wave * 32 + i * 16 + l4 * 4 + r;
      const float inv = 1.0f / l_s[i][r];
      bf16* op = O + ((size_t)(b * 1024 + srow)) * 2048 + h * 64;
#pragma unroll
      for (int jd = 0; jd < 4; ++jd)
        op[jd * 16 + l15] = (bf16)(o_acc[i][jd][r] * inv);
    }
}

// ---------------------------------------------------------------------------
// RMSNorm over last dim 2048: y = x * rsqrt(mean(x^2)+eps) * w
// ---------------------------------------------------------------------------
__global__ __launch_bounds__(256) void rmsnorm(
    const bf16* __restrict__ X, const bf16* __restrict__ W, bf16* __restrict__ Y)
{
  const int row = blockIdx.x;
  const int tid = threadIdx.x, wave = tid >> 6, lane = tid & 63;
  const bf16* xr = X + (size_t)row * 2048;
  const int base = tid * 8;
  const bf16x8 xv = *(const bf16x8*)(xr + base);
  float ss = 0.f;
  float xf[8];
#pragma unroll
  for (int j = 0; j < 8; ++j) { xf[j] = (float)xv[j]; ss += xf[j] * xf[j]; }
#pragma unroll
  for (int off = 32; off > 0; off >>= 1) ss += __shfl_xor(ss, off);
  __shared__ float red[4];
  if (lane == 0) red[wave] = ss;
  __syncthreads();
  const float tot = red[0] + red[1] + red[2] + red[3];
  const float rinv = rsqrtf(tot * (1.0f / 2048.0f) + 1e-5f);
  const bf16x8 wv = *(const bf16x8*)(W + base);
  bf16x8 yv;
#pragma unroll
  for (int j = 0; j < 8; ++j) yv[j] = (bf16)(xf[j] * rinv * (float)wv[j]);
  *(bf16x8*)(Y + (size_t)row * 2048 + base) = yv;
}

// ---------------------------------------------------------------------------
extern "C" void kernel_launch(void* const* d_in, const int* in_sizes, int n_in,
                              void* d_out, int out_size, void* d_ws, size_t ws_size,
                              hipStream_t stream) {
  const void* hs     = d_in[0];                // [2,1024,2048]  fp32 or bf16
  const int*  pos    = (const int*)d_in[1];    // [2,1024] int32
  const void* w_qkv  = d_in[2];                // [3072,2048]
  const void* w_o    = d_in[3];                // [2048,2048]
  const void* norm_w = d_in[4];                // [2048]

  char* ws = (char*)d_ws;
  bf16* hs_b    = (bf16*)(ws);                    //  8,388,608 B
  bf16* wqkv_b  = (bf16*)(ws + 8388608);          // 12,582,912 B
  bf16* w_o_b   = (bf16*)(ws + 20971520);         //  8,388,608 B
  bf16* normw_b = (bf16*)(ws + 29360128);         //      4,096 B
  int*  flag    = (int*) (ws + 29364224);         //         64 B
  bf16* qkv     = (bf16*)(ws + 29364288);         // 12,582,912 B
  bf16* Qr      = (bf16*)(ws + 41947200);         //  8,388,608 B
  bf16* Kr      = (bf16*)(ws + 50335808);         //  2,097,152 B
  bf16* Vtr     = (bf16*)(ws + 52432960);         //  2,097,152 B
  bf16* attn_o  = (bf16*)(ws + 54530112);         //  8,388,608 B (ends 62.9 MB)
  bf16* normed  = (bf16*)(ws);                    // alias hs_b (dead after gemm1)
  bf16* outb    = (bf16*)(ws + 8388608);          // alias wqkv_b (dead after gemm1)

  detect_dtype<<<1, 64, 0, stream>>>((const unsigned int*)hs, flag);
  convert_to_bf16<<<16384, 256, 0, stream>>>(hs,     hs_b,    4194304, flag);
  convert_to_bf16<<<24576, 256, 0, stream>>>(w_qkv,  wqkv_b,  6291456, flag);
  convert_to_bf16<<<16384, 256, 0, stream>>>(w_o,    w_o_b,   4194304, flag);
  convert_to_bf16<<<8,     256, 0, stream>>>(norm_w, normw_b, 2048,    flag);

  gemm_bt<<<dim3(24, 16), 256, 0, stream>>>(hs_b, wqkv_b, qkv, 2048, 3072, 2048);
  rope_relayout<<<24576, 256, 0, stream>>>(qkv, pos, Qr, Kr, Vtr);
  attn_kernel<<<dim3(8, 64), 256, 0, stream>>>(Qr, Kr, Vtr, attn_o);
  rmsnorm<<<2048, 256, 0, stream>>>(attn_o, normw_b, normed);
  gemm_bt<<<dim3(16, 16), 256, 0, stream>>>(normed, w_o_b, outb, 2048, 2048, 2048);

  write_out<<<16384, 256, 0, stream>>>(outb, d_out, 4194304, flag);
}

// Round 4
// 270.785 us; speedup vs baseline: 1.1663x; 1.1663x over previous
//
#include <hip/hip_runtime.h>
#include <hip/hip_bf16.h>
#include <cstdint>
#include <cstddef>

typedef __bf16 bf16;
typedef __bf16 bf16x4 __attribute__((ext_vector_type(4)));
typedef __bf16 bf16x8 __attribute__((ext_vector_type(8)));
typedef float  f32x4  __attribute__((ext_vector_type(4)));

// async global->LDS, 16B per lane. LDS dest = wave-uniform base + lane*16B.
__device__ __forceinline__ void async_copy16(const void* g, void* l) {
  __builtin_amdgcn_global_load_lds((const __attribute__((address_space(1))) void*)g,
                                   (__attribute__((address_space(3))) void*)l,
                                   16, 0, 0);
}

// ---------------------------------------------------------------------------
// Dtype detection (fp32 vs bf16 inputs): fp32 low-16 mantissa garbage decoded
// as bf16 has huge exponents ~50% of the time. flag=1 -> fp32 inputs.
// ---------------------------------------------------------------------------
__global__ void detect_dtype(const unsigned int* __restrict__ w, int* __restrict__ flag) {
  const int t = threadIdx.x;           // 64 threads
  int weird = 0;
#pragma unroll
  for (int c = 0; c < 2; ++c) {
    const unsigned int lo = w[c * 64 + t] & 0xffffu;
    const unsigned int ex = (lo >> 7) & 0xffu;
    if (ex >= 134u) ++weird;           // |bf16| >= 128 (or inf/nan)
  }
  const unsigned long long m1 = __ballot(weird >= 1);
  const unsigned long long m2 = __ballot(weird == 2);
  if (t == 0) *flag = (__popcll(m1) + __popcll(m2) >= 8) ? 1 : 0;
}

// Convert input (fp32 or bf16 per flag) to bf16, 4 elems/thread.
__global__ __launch_bounds__(256) void convert_to_bf16(
    const void* __restrict__ src, bf16* __restrict__ dst, int n4,
    const int* __restrict__ flag) {
  const int i = blockIdx.x * 256 + threadIdx.x;
  if (i >= n4) return;
  bf16x4 o;
  if (*flag) {
    const float4 v = ((const float4*)src)[i];
    o[0] = (bf16)v.x; o[1] = (bf16)v.y; o[2] = (bf16)v.z; o[3] = (bf16)v.w;
  } else {
    o = ((const bf16x4*)src)[i];
  }
  *(bf16x4*)(dst + (size_t)i * 4) = o;
}

// ---------------------------------------------------------------------------
// GEMM1 + fused neox RoPE epilogue.
//   A = hs_b [2048,2048], B = w_qkv_b [3072,2048] (both K-major).
//   Tile 64x128, BK=32, 4 waves in 2x2 (each 32x64 -> acc[2][4] of 16x16).
//   Epilogue: cols<2048 -> Q[B,NH,S,64] (x SCALE), <2560 -> K[B,NKV,S,64],
//             else V transposed -> Vt[B,NKV,64,S].  RoPE partner col^32 is
//             acc[i][j^2][r] (same lane, same reg).
// ---------------------------------------------------------------------------
__global__ __launch_bounds__(256) void gemm_qkv_rope(
    const bf16* __restrict__ A, const bf16* __restrict__ B,
    const int* __restrict__ pos,
    bf16* __restrict__ Q, bf16* __restrict__ K, bf16* __restrict__ V)
{
  __shared__ __align__(16) bf16 As[64 * 32];
  __shared__ __align__(16) bf16 Bs[128 * 32];
  const int tid = threadIdx.x, wave = tid >> 6, lane = tid & 63;
  const int l15 = lane & 15, l4 = lane >> 4;
  const int m0 = blockIdx.y * 64, n0 = blockIdx.x * 128;
  const int wm = (wave >> 1) * 32, wn = (wave & 1) * 64;
  const int KD = 2048;

  f32x4 acc[2][4] = {};

  const int ea = tid * 8;                  // 0..2047
  const int rowa = ea >> 5, ka = ea & 31;
  const bf16* Aa  = A + (size_t)(m0 + rowa) * KD + ka;
  const bf16* Bb0 = B + (size_t)(n0 + rowa) * KD + ka;
  const bf16* Bb1 = B + (size_t)(n0 + 64 + rowa) * KD + ka;

  for (int kt = 0; kt < KD; kt += 32) {
    async_copy16(Aa  + kt, As + ea);
    async_copy16(Bb0 + kt, Bs + ea);
    async_copy16(Bb1 + kt, Bs + 2048 + ea);
    __syncthreads();
    bf16x8 af[2], bfr[4];
#pragma unroll
    for (int i = 0; i < 2; ++i)
      af[i] = *(const bf16x8*)(As + (wm + i * 16 + l15) * 32 + l4 * 8);
#pragma unroll
    for (int j = 0; j < 4; ++j)
      bfr[j] = *(const bf16x8*)(Bs + (wn + j * 16 + l15) * 32 + l4 * 8);
#pragma unroll
    for (int i = 0; i < 2; ++i)
#pragma unroll
      for (int j = 0; j < 4; ++j)
        acc[i][j] = __builtin_amdgcn_mfma_f32_16x16x32_bf16(af[i], bfr[j], acc[i][j], 0, 0, 0);
    __syncthreads();
  }

  // ---- epilogue (C/D layout: col=lane&15, row=(lane>>4)*4+reg)
  if (n0 < 2560) {  // Q or K: rope in-register
    const bool isQ = (n0 < 2048);
#pragma unroll
    for (int i = 0; i < 2; ++i)
#pragma unroll
      for (int j = 0; j < 4; ++j) {
        const int col = n0 + wn + j * 16 + l15;
        const int hd = isQ ? col : (col - 2048);
        const int hh = hd >> 6, d = hd & 63;
        const int fi = d & 31;
        const float ifr = __expf((float)fi * -0.41007385554f);  // theta^(-fi/32)
#pragma unroll
        for (int r = 0; r < 4; ++r) {
          const int m = m0 + wm + i * 16 + l4 * 4 + r;
          const int b = m >> 10, s = m & 1023;
          const float ang = (float)pos[m] * ifr;
          float sn, cs;
          sincosf(ang, &sn, &cs);
          const float x  = acc[i][j][r];
          const float xp = acc[i][j ^ 2][r];   // partner (col^32)
          const float v = (d < 32) ? (x * cs - xp * sn) : (x * cs + xp * sn);
          if (isQ) Q[(((size_t)(b * 32 + hh)) * 1024 + s) * 64 + d] = (bf16)(v * 0.125f);
          else     K[(((size_t)(b * 8 + hh)) * 1024 + s) * 64 + d] = (bf16)v;
        }
      }
  } else {          // V: transpose to [B,NKV,64,S]
#pragma unroll
    for (int i = 0; i < 2; ++i)
#pragma unroll
      for (int j = 0; j < 4; ++j) {
        const int cv = n0 + wn + j * 16 + l15 - 2560;
        const int hh = cv >> 6, d = cv & 63;
#pragma unroll
        for (int r = 0; r < 4; ++r) {
          const int m = m0 + wm + i * 16 + l4 * 4 + r;
          const int b = m >> 10, s = m & 1023;
          V[(((size_t)(b * 8 + hh)) * 64 + d) * 1024 + s] = (bf16)acc[i][j][r];
        }
      }
  }
}

// ---------------------------------------------------------------------------
// Flash attention, causal GQA. Q-tile 64, K-tile 64. Grid (16, 64).
// 4 waves x 16 q-rows. Online softmax; P via swizzled LDS (C->A relayout).
// ---------------------------------------------------------------------------
__global__ __launch_bounds__(256) void attn_kernel(
    const bf16* __restrict__ Q, const bf16* __restrict__ K,
    const bf16* __restrict__ Vt, bf16* __restrict__ O)
{
  __shared__ __align__(16) bf16 Ks[2 * 64 * 32];   // [dchunk][key][32]
  __shared__ __align__(16) bf16 Vs[2 * 64 * 32];   // [kchunk][d][32]
  __shared__ __align__(16) bf16 Ps[64 * 64];       // swizzled P; also Q staging

  const int tid = threadIdx.x, wave = tid >> 6, lane = tid & 63;
  const int l15 = lane & 15, l4 = lane >> 4;
  const int qt = blockIdx.x, bh = blockIdx.y;
  const int b = bh >> 5, h = bh & 31, kvh = h >> 2;
  const int q0 = qt * 64;
  const bf16* Qb = Q + (((size_t)(b * 32 + h)) * 1024 + q0) * 64;
  const bf16* Kb = K + ((size_t)(b * 8 + kvh)) * 65536;
  const bf16* Vb = Vt + ((size_t)(b * 8 + kvh)) * 65536;

  // ---- stage Q tile [dchunk:2][row:64][32] into Ps, pull frags
#pragma unroll
  for (int c = 0; c < 2; ++c) {
    const int e = c * 2048 + tid * 8;
    const int row = (e & 2047) >> 5;
    const int dk = c * 32 + (e & 31);
    async_copy16(Qb + row * 64 + dk, Ps + e);
  }
  __syncthreads();
  bf16x8 aq[2];
#pragma unroll
  for (int s = 0; s < 2; ++s)
    aq[s] = *(const bf16x8*)(Ps + s * 2048 + (wave * 16 + l15) * 32 + l4 * 8);
  __syncthreads();

  float m_s[4], l_s[4];
  f32x4 o_acc[4] = {};
#pragma unroll
  for (int r = 0; r < 4; ++r) { m_s[r] = -3.0e4f; l_s[r] = 0.f; }

  const int nkt = qt + 1;   // causal: keys 0 .. q0+63
  for (int kt = 0; kt < nkt; ++kt) {
    const int k0 = kt * 64;
#pragma unroll
    for (int c = 0; c < 2; ++c) {
      const int e = c * 2048 + tid * 8;
      const int rr = (e & 2047) >> 5;
      const int dk = c * 32 + (e & 31);
      async_copy16(Kb + (size_t)(k0 + rr) * 64 + dk, Ks + e);
      async_copy16(Vb + (size_t)rr * 1024 + k0 + dk, Vs + e);
    }
    __syncthreads();

    // ---- S = Q K^T (scale pre-folded into Q)
    f32x4 sc[4] = {};
#pragma unroll
    for (int j = 0; j < 4; ++j) {
      const bf16x8 bk0 = *(const bf16x8*)(Ks + (j * 16 + l15) * 32 + l4 * 8);
      const bf16x8 bk1 = *(const bf16x8*)(Ks + 2048 + (j * 16 + l15) * 32 + l4 * 8);
      sc[j] = __builtin_amdgcn_mfma_f32_16x16x32_bf16(aq[0], bk0, sc[j], 0, 0, 0);
      sc[j] = __builtin_amdgcn_mfma_f32_16x16x32_bf16(aq[1], bk1, sc[j], 0, 0, 0);
    }

    // ---- mask + online softmax; write P (bf16) to swizzled LDS
#pragma unroll
    for (int r = 0; r < 4; ++r) {
      const int rr = wave * 16 + l4 * 4 + r;
      const int rg = q0 + rr;
      float mx = -3.0e4f;
#pragma unroll
      for (int j = 0; j < 4; ++j) {
        float v = sc[j][r];
        if (k0 + j * 16 + l15 > rg) v = -3.0e4f;
        sc[j][r] = v;
        mx = fmaxf(mx, v);
      }
#pragma unroll
      for (int off = 1; off < 16; off <<= 1) mx = fmaxf(mx, __shfl_xor(mx, off));
      const float mnew = fmaxf(m_s[r], mx);
      const float alpha = __expf(m_s[r] - mnew);
      m_s[r] = mnew;
      float rs = 0.f;
      const int sw = rr & 7;
#pragma unroll
      for (int j = 0; j < 4; ++j) {
        const float pv = __expf(sc[j][r] - mnew);
        rs += pv;
        const int k = j * 16 + l15;
        Ps[rr * 64 + (((k >> 3) ^ sw) << 3) + (k & 7)] = (bf16)pv;
      }
#pragma unroll
      for (int off = 1; off < 16; off <<= 1) rs += __shfl_xor(rs, off);
      l_s[r] = l_s[r] * alpha + rs;
#pragma unroll
      for (int jd = 0; jd < 4; ++jd) o_acc[jd][r] *= alpha;
    }
    __syncthreads();

    // ---- O += P V
#pragma unroll
    for (int ks = 0; ks < 2; ++ks) {
      const int rr = wave * 16 + l15;
      const int g = (ks * 4 + l4) ^ (rr & 7);
      const bf16x8 ap = *(const bf16x8*)(Ps + rr * 64 + g * 8);
#pragma unroll
      for (int jd = 0; jd < 4; ++jd) {
        const bf16x8 bv = *(const bf16x8*)(Vs + ks * 2048 + (jd * 16 + l15) * 32 + l4 * 8);
        o_acc[jd] = __builtin_amdgcn_mfma_f32_16x16x32_bf16(ap, bv, o_acc[jd], 0, 0, 0);
      }
    }
    __syncthreads();
  }

  // ---- epilogue: O /= l, write [B*S, NH*64]
#pragma unroll
  for (int r = 0; r < 4; ++r) {
    const int srow = q0 + wave * 16 + l4 * 4 + r;
    const float inv = 1.0f / l_s[r];
    bf16* op = O + ((size_t)(b * 1024 + srow)) * 2048 + h * 64;
#pragma unroll
    for (int jd = 0; jd < 4; ++jd)
      op[jd * 16 + l15] = (bf16)(o_acc[jd][r] * inv);
  }
}

// ---------------------------------------------------------------------------
// RMSNorm over last dim 2048: y = x * rsqrt(mean(x^2)+eps) * w
// ---------------------------------------------------------------------------
__global__ __launch_bounds__(256) void rmsnorm(
    const bf16* __restrict__ X, const bf16* __restrict__ W, bf16* __restrict__ Y)
{
  const int row = blockIdx.x;
  const int tid = threadIdx.x, wave = tid >> 6, lane = tid & 63;
  const bf16* xr = X + (size_t)row * 2048;
  const int base = tid * 8;
  const bf16x8 xv = *(const bf16x8*)(xr + base);
  float ss = 0.f;
  float xf[8];
#pragma unroll
  for (int j = 0; j < 8; ++j) { xf[j] = (float)xv[j]; ss += xf[j] * xf[j]; }
#pragma unroll
  for (int off = 32; off > 0; off >>= 1) ss += __shfl_xor(ss, off);
  __shared__ float red[4];
  if (lane == 0) red[wave] = ss;
  __syncthreads();
  const float tot = red[0] + red[1] + red[2] + red[3];
  const float rinv = rsqrtf(tot * (1.0f / 2048.0f) + 1e-5f);
  const bf16x8 wv = *(const bf16x8*)(W + base);
  bf16x8 yv;
#pragma unroll
  for (int j = 0; j < 8; ++j) yv[j] = (bf16)(xf[j] * rinv * (float)wv[j]);
  *(bf16x8*)(Y + (size_t)row * 2048 + base) = yv;
}

// ---------------------------------------------------------------------------
// GEMM2: out[2048,2048] = normed [2048,2048] x w_o[2048,2048]^T, dtype-steered
// output write (fp32 if flag else bf16). Tile 64x128, BK=32.
// ---------------------------------------------------------------------------
__global__ __launch_bounds__(256) void gemm_out(
    const bf16* __restrict__ A, const bf16* __restrict__ B,
    void* __restrict__ out, const int* __restrict__ flag)
{
  __shared__ __align__(16) bf16 As[64 * 32];
  __shared__ __align__(16) bf16 Bs[128 * 32];
  const int tid = threadIdx.x, wave = tid >> 6, lane = tid & 63;
  const int l15 = lane & 15, l4 = lane >> 4;
  const int m0 = blockIdx.y * 64, n0 = blockIdx.x * 128;
  const int wm = (wave >> 1) * 32, wn = (wave & 1) * 64;
  const int KD = 2048;

  f32x4 acc[2][4] = {};

  const int ea = tid * 8;
  const int rowa = ea >> 5, ka = ea & 31;
  const bf16* Aa  = A + (size_t)(m0 + rowa) * KD + ka;
  const bf16* Bb0 = B + (size_t)(n0 + rowa) * KD + ka;
  const bf16* Bb1 = B + (size_t)(n0 + 64 + rowa) * KD + ka;

  for (int kt = 0; kt < KD; kt += 32) {
    async_copy16(Aa  + kt, As + ea);
    async_copy16(Bb0 + kt, Bs + ea);
    async_copy16(Bb1 + kt, Bs + 2048 + ea);
    __syncthreads();
    bf16x8 af[2], bfr[4];
#pragma unroll
    for (int i = 0; i < 2; ++i)
      af[i] = *(const bf16x8*)(As + (wm + i * 16 + l15) * 32 + l4 * 8);
#pragma unroll
    for (int j = 0; j < 4; ++j)
      bfr[j] = *(const bf16x8*)(Bs + (wn + j * 16 + l15) * 32 + l4 * 8);
#pragma unroll
    for (int i = 0; i < 2; ++i)
#pragma unroll
      for (int j = 0; j < 4; ++j)
        acc[i][j] = __builtin_amdgcn_mfma_f32_16x16x32_bf16(af[i], bfr[j], acc[i][j], 0, 0, 0);
    __syncthreads();
  }

  const bool f32out = (*flag != 0);
#pragma unroll
  for (int i = 0; i < 2; ++i)
#pragma unroll
    for (int j = 0; j < 4; ++j) {
      const int col = n0 + wn + j * 16 + l15;
#pragma unroll
      for (int r = 0; r < 4; ++r) {
        const size_t idx = (size_t)(m0 + wm + i * 16 + l4 * 4 + r) * 2048 + col;
        if (f32out) ((float*)out)[idx] = acc[i][j][r];
        else        ((bf16*)out)[idx]  = (bf16)acc[i][j][r];
      }
    }
}

// ---------------------------------------------------------------------------
extern "C" void kernel_launch(void* const* d_in, const int* in_sizes, int n_in,
                              void* d_out, int out_size, void* d_ws, size_t ws_size,
                              hipStream_t stream) {
  const void* hs     = d_in[0];                // [2,1024,2048]  fp32 (or bf16)
  const int*  pos    = (const int*)d_in[1];    // [2,1024] int32
  const void* w_qkv  = d_in[2];                // [3072,2048]
  const void* w_o    = d_in[3];                // [2048,2048]
  const void* norm_w = d_in[4];                // [2048]

  char* ws = (char*)d_ws;
  bf16* hs_b    = (bf16*)(ws);                    //  8,388,608
  bf16* wqkv_b  = (bf16*)(ws + 8388608);          // 12,582,912
  bf16* w_o_b   = (bf16*)(ws + 20971520);         //  8,388,608
  bf16* normw_b = (bf16*)(ws + 29360128);         //      4,096
  int*  flag    = (int*) (ws + 29364224);         //         64
  bf16* Qr      = (bf16*)(ws + 29364288);         //  8,388,608
  bf16* Kr      = (bf16*)(ws + 37752896);         //  2,097,152
  bf16* Vtr     = (bf16*)(ws + 39850048);         //  2,097,152
  bf16* attn_o  = (bf16*)(ws + 41947200);         //  8,388,608 (ends 50.3 MB)
  bf16* normed  = hs_b;                           // alias (dead after gemm1)

  detect_dtype<<<1, 64, 0, stream>>>((const unsigned int*)hs, flag);
  convert_to_bf16<<<4096, 256, 0, stream>>>(hs,     hs_b,    1048576, flag);
  convert_to_bf16<<<6144, 256, 0, stream>>>(w_qkv,  wqkv_b,  1572864, flag);
  convert_to_bf16<<<4096, 256, 0, stream>>>(w_o,    w_o_b,   1048576, flag);
  convert_to_bf16<<<2,    256, 0, stream>>>(norm_w, normw_b, 512,     flag);

  gemm_qkv_rope<<<dim3(24, 32), 256, 0, stream>>>(hs_b, wqkv_b, pos, Qr, Kr, Vtr);
  attn_kernel<<<dim3(16, 64), 256, 0, stream>>>(Qr, Kr, Vtr, attn_o);
  rmsnorm<<<2048, 256, 0, stream>>>(attn_o, normw_b, normed);
  gemm_out<<<dim3(16, 32), 256, 0, stream>>>(normed, w_o_b, d_out, flag);
}

// Round 6
// 225.893 us; speedup vs baseline: 1.3980x; 1.1987x over previous
//
#include <hip/hip_runtime.h>
#include <hip/hip_bf16.h>
#include <cstdint>
#include <cstddef>

typedef __bf16 bf16;
typedef __bf16 bf16x4 __attribute__((ext_vector_type(4)));
typedef __bf16 bf16x8 __attribute__((ext_vector_type(8)));
typedef float  f32x4  __attribute__((ext_vector_type(4)));

// async global->LDS, 16B per lane. LDS dest = wave-uniform base + lane*16B.
__device__ __forceinline__ void async_copy16(const void* g, void* l) {
  __builtin_amdgcn_global_load_lds((const __attribute__((address_space(1))) void*)g,
                                   (__attribute__((address_space(3))) void*)l,
                                   16, 0, 0);
}

// ---------------------------------------------------------------------------
// Dtype detection: fp32 low-16 mantissa garbage decoded as bf16 has huge
// exponents ~50% of the time. flag=1 -> fp32 inputs.
// ---------------------------------------------------------------------------
__global__ void detect_dtype(const unsigned int* __restrict__ w, int* __restrict__ flag) {
  const int t = threadIdx.x;           // 64 threads
  int weird = 0;
#pragma unroll
  for (int c = 0; c < 2; ++c) {
    const unsigned int lo = w[c * 64 + t] & 0xffffu;
    const unsigned int ex = (lo >> 7) & 0xffu;
    if (ex >= 134u) ++weird;           // |bf16| >= 128 (or inf/nan)
  }
  const unsigned long long m1 = __ballot(weird >= 1);
  const unsigned long long m2 = __ballot(weird == 2);
  if (t == 0) *flag = (__popcll(m1) + __popcll(m2) >= 8) ? 1 : 0;
}

// ---------------------------------------------------------------------------
// Fused convert: all four float inputs -> bf16 in one dispatch (x4 units).
// ---------------------------------------------------------------------------
__global__ __launch_bounds__(256) void convert_all(
    const void* __restrict__ s0, const void* __restrict__ s1,
    const void* __restrict__ s2, const void* __restrict__ s3,
    bf16* __restrict__ d0, bf16* __restrict__ d1,
    bf16* __restrict__ d2, bf16* __restrict__ d3,
    const int* __restrict__ flag) {
  const int i = blockIdx.x * 256 + threadIdx.x;
  if (i >= 3670528) return;
  const void* src; bf16* dst; int off;
  if      (i < 1048576) { src = s0; dst = d0; off = i; }
  else if (i < 2621440) { src = s1; dst = d1; off = i - 1048576; }
  else if (i < 3670016) { src = s2; dst = d2; off = i - 2621440; }
  else                  { src = s3; dst = d3; off = i - 3670016; }
  bf16x4 o;
  if (*flag) {
    const float4 v = ((const float4*)src)[off];
    o[0] = (bf16)v.x; o[1] = (bf16)v.y; o[2] = (bf16)v.z; o[3] = (bf16)v.w;
  } else {
    o = ((const bf16x4*)src)[off];
  }
  *(bf16x4*)(dst + (size_t)off * 4) = o;
}

// ---------------------------------------------------------------------------
// GEMM1 + fused neox RoPE epilogue. (unchanged — passing since round 4)
// ---------------------------------------------------------------------------
__global__ __launch_bounds__(256) void gemm_qkv_rope(
    const bf16* __restrict__ A, const bf16* __restrict__ B,
    const int* __restrict__ pos,
    bf16* __restrict__ Q, bf16* __restrict__ K, bf16* __restrict__ V)
{
  __shared__ __align__(16) bf16 As[64 * 32];
  __shared__ __align__(16) bf16 Bs[128 * 32];
  const int tid = threadIdx.x, wave = tid >> 6, lane = tid & 63;
  const int l15 = lane & 15, l4 = lane >> 4;
  const int m0 = blockIdx.y * 64, n0 = blockIdx.x * 128;
  const int wm = (wave >> 1) * 32, wn = (wave & 1) * 64;
  const int KD = 2048;

  f32x4 acc[2][4] = {};

  const int ea = tid * 8;
  const int rowa = ea >> 5, ka = ea & 31;
  const bf16* Aa  = A + (size_t)(m0 + rowa) * KD + ka;
  const bf16* Bb0 = B + (size_t)(n0 + rowa) * KD + ka;
  const bf16* Bb1 = B + (size_t)(n0 + 64 + rowa) * KD + ka;

  for (int kt = 0; kt < KD; kt += 32) {
    async_copy16(Aa  + kt, As + ea);
    async_copy16(Bb0 + kt, Bs + ea);
    async_copy16(Bb1 + kt, Bs + 2048 + ea);
    __syncthreads();
    bf16x8 af[2], bfr[4];
#pragma unroll
    for (int i = 0; i < 2; ++i)
      af[i] = *(const bf16x8*)(As + (wm + i * 16 + l15) * 32 + l4 * 8);
#pragma unroll
    for (int j = 0; j < 4; ++j)
      bfr[j] = *(const bf16x8*)(Bs + (wn + j * 16 + l15) * 32 + l4 * 8);
#pragma unroll
    for (int i = 0; i < 2; ++i)
#pragma unroll
      for (int j = 0; j < 4; ++j)
        acc[i][j] = __builtin_amdgcn_mfma_f32_16x16x32_bf16(af[i], bfr[j], acc[i][j], 0, 0, 0);
    __syncthreads();
  }

  if (n0 < 2560) {  // Q or K: rope in-register
    const bool isQ = (n0 < 2048);
#pragma unroll
    for (int i = 0; i < 2; ++i)
#pragma unroll
      for (int j = 0; j < 4; ++j) {
        const int col = n0 + wn + j * 16 + l15;
        const int hd = isQ ? col : (col - 2048);
        const int hh = hd >> 6, d = hd & 63;
        const int fi = d & 31;
        const float ifr = __expf((float)fi * -0.41007385554f);  // theta^(-fi/32)
#pragma unroll
        for (int r = 0; r < 4; ++r) {
          const int m = m0 + wm + i * 16 + l4 * 4 + r;
          const int b = m >> 10, s = m & 1023;
          const float ang = (float)pos[m] * ifr;
          float sn, cs;
          sincosf(ang, &sn, &cs);
          const float x  = acc[i][j][r];
          const float xp = acc[i][j ^ 2][r];   // partner (col^32)
          const float v = (d < 32) ? (x * cs - xp * sn) : (x * cs + xp * sn);
          if (isQ) Q[(((size_t)(b * 32 + hh)) * 1024 + s) * 64 + d] = (bf16)(v * 0.125f);
          else     K[(((size_t)(b * 8 + hh)) * 1024 + s) * 64 + d] = (bf16)v;
        }
      }
  } else {          // V: transpose to [B,NKV,64,S]
#pragma unroll
    for (int i = 0; i < 2; ++i)
#pragma unroll
      for (int j = 0; j < 4; ++j) {
        const int cv = n0 + wn + j * 16 + l15 - 2560;
        const int hh = cv >> 6, d = cv & 63;
#pragma unroll
        for (int r = 0; r < 4; ++r) {
          const int m = m0 + wm + i * 16 + l4 * 4 + r;
          const int b = m >> 10, s = m & 1023;
          V[(((size_t)(b * 8 + hh)) * 64 + d) * 1024 + s] = (bf16)acc[i][j][r];
        }
      }
  }
}

// ---------------------------------------------------------------------------
// Flash attention, causal GQA, balanced diagonal pairs, ONLINE softmax
// (round-4 numerics: running max + fp32 butterfly row-sum + alpha rescale).
// Block (ip, b*32+h): Q-tiles qlo=ip*64 and qhi=(15-ip)*64, shared K-loop
// with K-tile=128. 512 uniform blocks.
// ---------------------------------------------------------------------------
__global__ __launch_bounds__(256) void attn_kernel(
    const bf16* __restrict__ Q, const bf16* __restrict__ K,
    const bf16* __restrict__ Vt, bf16* __restrict__ O)
{
  __shared__ __align__(16) bf16 Ks[2 * 128 * 32];   // 16KB [dchunk][key][32]
  __shared__ __align__(16) bf16 Vs[4 * 64 * 32];    // 16KB [kchunk][d][32]
  __shared__ __align__(16) bf16 Ps[4 * 128 * 40];   // 40KB [kchunk][q][40]; Q-stage reuse

  const int tid = threadIdx.x, wave = tid >> 6, lane = tid & 63;
  const int l15 = lane & 15, l4 = lane >> 4;
  const int ip = blockIdx.x, bh = blockIdx.y;
  const int b = bh >> 5, h = bh & 31, kvh = h >> 2;
  const int qlo = ip * 64, qhi = (15 - ip) * 64;
  const bf16* Qb = Q + ((size_t)(b * 32 + h)) * 65536;
  const bf16* Kb = K + ((size_t)(b * 8 + kvh)) * 65536;
  const bf16* Vb = Vt + ((size_t)(b * 8 + kvh)) * 65536;

  // ---- stage Q [dchunk:2][row:128][32] into Ps (rows 0-63 lo, 64-127 hi)
#pragma unroll
  for (int c = 0; c < 4; ++c) {
    const int e = c * 2048 + tid * 8;
    const int dchunk = e >> 12;
    const int row = (e & 4095) >> 5;
    const int qb = (row < 64) ? qlo : qhi;
    async_copy16(Qb + (size_t)(qb + (row & 63)) * 64 + dchunk * 32 + (e & 31), Ps + e);
  }
  __syncthreads();
  bf16x8 aq[2][2];   // [half][dchunk]
#pragma unroll
  for (int i = 0; i < 2; ++i)
#pragma unroll
    for (int s = 0; s < 2; ++s)
      aq[i][s] = *(const bf16x8*)(Ps + s * 4096 + (i * 64 + wave * 16 + l15) * 32 + l4 * 8);
  __syncthreads();   // Ps free for P reuse

  float m_s[2][4], l_s[2][4];
  f32x4 o_acc[2][4] = {};   // [half][jd]
#pragma unroll
  for (int i = 0; i < 2; ++i)
#pragma unroll
    for (int r = 0; r < 4; ++r) { m_s[i][r] = -3.0e4f; l_s[i][r] = 0.f; }

  const int nkt = (1151 - 64 * ip) >> 7;   // hi tile: ceil((qhi+64)/128)
  for (int kt = 0; kt < nkt; ++kt) {
    const int k0 = kt * 128;
    const bool lo_act = (k0 < (ip + 1) * 64);
    // ---- stage K [2][128][32] and V [4][64][32]
#pragma unroll
    for (int c = 0; c < 4; ++c) {
      const int e = c * 2048 + tid * 8;
      const int dchunk = e >> 12;
      const int krow = (e & 4095) >> 5;
      async_copy16(Kb + (size_t)(k0 + krow) * 64 + dchunk * 32 + (e & 31), Ks + e);
      const int kc = e >> 11;
      const int drow = (e & 2047) >> 5;
      async_copy16(Vb + (size_t)drow * 1024 + k0 + kc * 32 + (e & 31), Vs + e);
    }
    __syncthreads();

    // ---- S = Q K^T (scale pre-folded into Q), both halves
    f32x4 sc[2][8] = {};
#pragma unroll
    for (int j = 0; j < 8; ++j) {
      const bf16x8 bk0 = *(const bf16x8*)(Ks + (j * 16 + l15) * 32 + l4 * 8);
      const bf16x8 bk1 = *(const bf16x8*)(Ks + 4096 + (j * 16 + l15) * 32 + l4 * 8);
      sc[1][j] = __builtin_amdgcn_mfma_f32_16x16x32_bf16(aq[1][0], bk0, sc[1][j], 0, 0, 0);
      sc[1][j] = __builtin_amdgcn_mfma_f32_16x16x32_bf16(aq[1][1], bk1, sc[1][j], 0, 0, 0);
      if (lo_act) {
        sc[0][j] = __builtin_amdgcn_mfma_f32_16x16x32_bf16(aq[0][0], bk0, sc[0][j], 0, 0, 0);
        sc[0][j] = __builtin_amdgcn_mfma_f32_16x16x32_bf16(aq[0][1], bk1, sc[0][j], 0, 0, 0);
      }
    }

    // ---- mask + ONLINE softmax; write P (bf16, <=1) to [kc][q][40]
#pragma unroll
    for (int hh = 0; hh < 2; ++hh) {
      if (hh == 0 && !lo_act) continue;
      const int qb = hh ? qhi : qlo;
#pragma unroll
      for (int r = 0; r < 4; ++r) {
        const int rl = wave * 16 + l4 * 4 + r;
        const int rg = qb + rl;
        float mx = -3.0e4f;
#pragma unroll
        for (int j = 0; j < 8; ++j) {
          float v = sc[hh][j][r];
          if (k0 + j * 16 + l15 > rg) v = -3.0e4f;
          sc[hh][j][r] = v;
          mx = fmaxf(mx, v);
        }
#pragma unroll
        for (int off = 1; off < 16; off <<= 1) mx = fmaxf(mx, __shfl_xor(mx, off));
        const float mnew = fmaxf(m_s[hh][r], mx);
        const float alpha = __expf(m_s[hh][r] - mnew);
        m_s[hh][r] = mnew;
        float rs = 0.f;
#pragma unroll
        for (int j = 0; j < 8; ++j) {
          const float pv = __expf(sc[hh][j][r] - mnew);
          rs += pv;
          Ps[(j >> 1) * 5120 + (hh * 64 + rl) * 40 + (j & 1) * 16 + l15] = (bf16)pv;
        }
#pragma unroll
        for (int off = 1; off < 16; off <<= 1) rs += __shfl_xor(rs, off);
        l_s[hh][r] = l_s[hh][r] * alpha + rs;
#pragma unroll
        for (int jd = 0; jd < 4; ++jd) o_acc[hh][jd][r] *= alpha;
      }
    }
    __syncthreads();

    // ---- O += P V
#pragma unroll
    for (int ks = 0; ks < 4; ++ks) {
      bf16x8 bv[4];
#pragma unroll
      for (int jd = 0; jd < 4; ++jd)
        bv[jd] = *(const bf16x8*)(Vs + ks * 2048 + (jd * 16 + l15) * 32 + l4 * 8);
#pragma unroll
      for (int hh = 0; hh < 2; ++hh) {
        if (hh == 0 && !lo_act) continue;
        const bf16x8 ap = *(const bf16x8*)(Ps + ks * 5120 + (hh * 64 + wave * 16 + l15) * 40 + l4 * 8);
#pragma unroll
        for (int jd = 0; jd < 4; ++jd)
          o_acc[hh][jd] = __builtin_amdgcn_mfma_f32_16x16x32_bf16(ap, bv[jd], o_acc[hh][jd], 0, 0, 0);
      }
    }
    __syncthreads();
  }

  // ---- epilogue: O /= l, write [B*S, NH*64]
#pragma unroll
  for (int hh = 0; hh < 2; ++hh) {
    const int qb = hh ? qhi : qlo;
#pragma unroll
    for (int r = 0; r < 4; ++r) {
      const float inv = 1.0f / l_s[hh][r];
      const int srow = qb + wave * 16 + l4 * 4 + r;
      bf16* op = O + ((size_t)(b * 1024 + srow)) * 2048 + h * 64;
#pragma unroll
      for (int jd = 0; jd < 4; ++jd)
        op[jd * 16 + l15] = (bf16)(o_acc[hh][jd][r] * inv);
    }
  }
}

// ---------------------------------------------------------------------------
// RMSNorm over last dim 2048.
// ---------------------------------------------------------------------------
__global__ __launch_bounds__(256) void rmsnorm(
    const bf16* __restrict__ X, const bf16* __restrict__ W, bf16* __restrict__ Y)
{
  const int row = blockIdx.x;
  const int tid = threadIdx.x, wave = tid >> 6, lane = tid & 63;
  const bf16* xr = X + (size_t)row * 2048;
  const int base = tid * 8;
  const bf16x8 xv = *(const bf16x8*)(xr + base);
  float ss = 0.f;
  float xf[8];
#pragma unroll
  for (int j = 0; j < 8; ++j) { xf[j] = (float)xv[j]; ss += xf[j] * xf[j]; }
#pragma unroll
  for (int off = 32; off > 0; off >>= 1) ss += __shfl_xor(ss, off);
  __shared__ float red[4];
  if (lane == 0) red[wave] = ss;
  __syncthreads();
  const float tot = red[0] + red[1] + red[2] + red[3];
  const float rinv = rsqrtf(tot * (1.0f / 2048.0f) + 1e-5f);
  const bf16x8 wv = *(const bf16x8*)(W + base);
  bf16x8 yv;
#pragma unroll
  for (int j = 0; j < 8; ++j) yv[j] = (bf16)(xf[j] * rinv * (float)wv[j]);
  *(bf16x8*)(Y + (size_t)row * 2048 + base) = yv;
}

// ---------------------------------------------------------------------------
// GEMM2 with dtype-steered output write. (unchanged — passing since round 4)
// ---------------------------------------------------------------------------
__global__ __launch_bounds__(256) void gemm_out(
    const bf16* __restrict__ A, const bf16* __restrict__ B,
    void* __restrict__ out, const int* __restrict__ flag)
{
  __shared__ __align__(16) bf16 As[64 * 32];
  __shared__ __align__(16) bf16 Bs[128 * 32];
  const int tid = threadIdx.x, wave = tid >> 6, lane = tid & 63;
  const int l15 = lane & 15, l4 = lane >> 4;
  const int m0 = blockIdx.y * 64, n0 = blockIdx.x * 128;
  const int wm = (wave >> 1) * 32, wn = (wave & 1) * 64;
  const int KD = 2048;

  f32x4 acc[2][4] = {};

  const int ea = tid * 8;
  const int rowa = ea >> 5, ka = ea & 31;
  const bf16* Aa  = A + (size_t)(m0 + rowa) * KD + ka;
  const bf16* Bb0 = B + (size_t)(n0 + rowa) * KD + ka;
  const bf16* Bb1 = B + (size_t)(n0 + 64 + rowa) * KD + ka;

  for (int kt = 0; kt < KD; kt += 32) {
    async_copy16(Aa  + kt, As + ea);
    async_copy16(Bb0 + kt, Bs + ea);
    async_copy16(Bb1 + kt, Bs + 2048 + ea);
    __syncthreads();
    bf16x8 af[2], bfr[4];
#pragma unroll
    for (int i = 0; i < 2; ++i)
      af[i] = *(const bf16x8*)(As + (wm + i * 16 + l15) * 32 + l4 * 8);
#pragma unroll
    for (int j = 0; j < 4; ++j)
      bfr[j] = *(const bf16x8*)(Bs + (wn + j * 16 + l15) * 32 + l4 * 8);
#pragma unroll
    for (int i = 0; i < 2; ++i)
#pragma unroll
      for (int j = 0; j < 4; ++j)
        acc[i][j] = __builtin_amdgcn_mfma_f32_16x16x32_bf16(af[i], bfr[j], acc[i][j], 0, 0, 0);
    __syncthreads();
  }

  const bool f32out = (*flag != 0);
#pragma unroll
  for (int i = 0; i < 2; ++i)
#pragma unroll
    for (int j = 0; j < 4; ++j) {
      const int col = n0 + wn + j * 16 + l15;
#pragma unroll
      for (int r = 0; r < 4; ++r) {
        const size_t idx = (size_t)(m0 + wm + i * 16 + l4 * 4 + r) * 2048 + col;
        if (f32out) ((float*)out)[idx] = acc[i][j][r];
        else        ((bf16*)out)[idx]  = (bf16)acc[i][j][r];
      }
    }
}

// ---------------------------------------------------------------------------
extern "C" void kernel_launch(void* const* d_in, const int* in_sizes, int n_in,
                              void* d_out, int out_size, void* d_ws, size_t ws_size,
                              hipStream_t stream) {
  const void* hs     = d_in[0];                // [2,1024,2048]  fp32 (or bf16)
  const int*  pos    = (const int*)d_in[1];    // [2,1024] int32
  const void* w_qkv  = d_in[2];                // [3072,2048]
  const void* w_o    = d_in[3];                // [2048,2048]
  const void* norm_w = d_in[4];                // [2048]

  char* ws = (char*)d_ws;
  bf16* hs_b    = (bf16*)(ws);                    //  8,388,608
  bf16* wqkv_b  = (bf16*)(ws + 8388608);          // 12,582,912
  bf16* w_o_b   = (bf16*)(ws + 20971520);         //  8,388,608
  bf16* normw_b = (bf16*)(ws + 29360128);         //      4,096
  int*  flag    = (int*) (ws + 29364224);         //         64
  bf16* Qr      = (bf16*)(ws + 29364288);         //  8,388,608
  bf16* Kr      = (bf16*)(ws + 37752896);         //  2,097,152
  bf16* Vtr     = (bf16*)(ws + 39850048);         //  2,097,152
  bf16* attn_o  = (bf16*)(ws + 41947200);         //  8,388,608 (ends 50.3 MB)
  bf16* normed  = hs_b;                           // alias (dead after gemm1)

  detect_dtype<<<1, 64, 0, stream>>>((const unsigned int*)hs, flag);
  convert_all<<<14338, 256, 0, stream>>>(hs, w_qkv, w_o, norm_w,
                                         hs_b, wqkv_b, w_o_b, normw_b, flag);

  gemm_qkv_rope<<<dim3(24, 32), 256, 0, stream>>>(hs_b, wqkv_b, pos, Qr, Kr, Vtr);
  attn_kernel<<<dim3(8, 64), 256, 0, stream>>>(Qr, Kr, Vtr, attn_o);
  rmsnorm<<<2048, 256, 0, stream>>>(attn_o, normw_b, normed);
  gemm_out<<<dim3(16, 32), 256, 0, stream>>>(normed, w_o_b, d_out, flag);
}

// Round 7
// 213.098 us; speedup vs baseline: 1.4820x; 1.0600x over previous
//
#include <hip/hip_runtime.h>
#include <hip/hip_bf16.h>
#include <cstdint>
#include <cstddef>

typedef __bf16 bf16;
typedef __bf16 bf16x4 __attribute__((ext_vector_type(4)));
typedef __bf16 bf16x8 __attribute__((ext_vector_type(8)));
typedef float  f32x4  __attribute__((ext_vector_type(4)));

// async global->LDS, 16B per lane. LDS dest = wave-uniform base + lane*16B.
__device__ __forceinline__ void async_copy16(const void* g, void* l) {
  __builtin_amdgcn_global_load_lds((const __attribute__((address_space(1))) void*)g,
                                   (__attribute__((address_space(3))) void*)l,
                                   16, 0, 0);
}

// ---------------------------------------------------------------------------
// Dtype detection + ssum zero-init. flag=1 -> fp32 inputs.
// ---------------------------------------------------------------------------
__global__ __launch_bounds__(256) void detect_dtype(
    const unsigned int* __restrict__ w, int* __restrict__ flag,
    float* __restrict__ ssum) {
  const int t = threadIdx.x;
  // zero the 2048-float ssum buffer (d_ws is poisoned each launch)
  ((float4*)ssum)[t * 2]     = make_float4(0.f, 0.f, 0.f, 0.f);
  ((float4*)ssum)[t * 2 + 1] = make_float4(0.f, 0.f, 0.f, 0.f);
  if (t < 64) {
    int weird = 0;
#pragma unroll
    for (int c = 0; c < 2; ++c) {
      const unsigned int lo = w[c * 64 + t] & 0xffffu;
      const unsigned int ex = (lo >> 7) & 0xffu;
      if (ex >= 134u) ++weird;           // |bf16| >= 128 (or inf/nan)
    }
    const unsigned long long m1 = __ballot(weird >= 1);
    const unsigned long long m2 = __ballot(weird == 2);
    if (t == 0) *flag = (__popcll(m1) + __popcll(m2) >= 8) ? 1 : 0;
  }
}

// ---------------------------------------------------------------------------
// Fused convert (float4-unit indexed):
//   [0, 1048576)           hs
//   [1048576, 2621440)     w_qkv
//   [2621440, 3670016)     w_o  (x norm_w[k] folded in)
// ---------------------------------------------------------------------------
__global__ __launch_bounds__(256) void convert_all(
    const void* __restrict__ s0, const void* __restrict__ s1,
    const void* __restrict__ s2, const void* __restrict__ s3,
    bf16* __restrict__ d0, bf16* __restrict__ d1, bf16* __restrict__ d2,
    const int* __restrict__ flag) {
  const int i = blockIdx.x * 256 + threadIdx.x;
  if (i >= 3670016) return;
  const bool f32 = (*flag != 0);
  const void* src; bf16* dst; int off; bool fold = false;
  if      (i < 1048576) { src = s0; dst = d0; off = i; }
  else if (i < 2621440) { src = s1; dst = d1; off = i - 1048576; }
  else                  { src = s2; dst = d2; off = i - 2621440; fold = true; }
  float v[4];
  if (f32) {
    const float4 t = ((const float4*)src)[off];
    v[0] = t.x; v[1] = t.y; v[2] = t.z; v[3] = t.w;
  } else {
    const bf16x4 t = ((const bf16x4*)src)[off];
#pragma unroll
    for (int j = 0; j < 4; ++j) v[j] = (float)t[j];
  }
  if (fold) {
    const int k0 = (off * 4) & 2047;
#pragma unroll
    for (int j = 0; j < 4; ++j) {
      const float w = f32 ? ((const float*)s3)[k0 + j] : (float)((const bf16*)s3)[k0 + j];
      v[j] *= w;
    }
  }
  bf16x4 o;
#pragma unroll
  for (int j = 0; j < 4; ++j) o[j] = (bf16)v[j];
  *(bf16x4*)(dst + (size_t)off * 4) = o;
}

// ---------------------------------------------------------------------------
// GEMM1 + fused neox RoPE epilogue. Tile 64x128, BK=64 (2 k-steps/barrier).
// LDS: As [kc:2][row:64][32], Bs [kc:2][row:128][32].
// ---------------------------------------------------------------------------
__global__ __launch_bounds__(256) void gemm_qkv_rope(
    const bf16* __restrict__ A, const bf16* __restrict__ B,
    const int* __restrict__ pos,
    bf16* __restrict__ Q, bf16* __restrict__ K, bf16* __restrict__ V)
{
  __shared__ __align__(16) bf16 As[2 * 64 * 32];    //  8KB
  __shared__ __align__(16) bf16 Bs[2 * 128 * 32];   // 16KB
  const int tid = threadIdx.x, wave = tid >> 6, lane = tid & 63;
  const int l15 = lane & 15, l4 = lane >> 4;
  const int m0 = blockIdx.y * 64, n0 = blockIdx.x * 128;
  const int wm = (wave >> 1) * 32, wn = (wave & 1) * 64;
  const int KD = 2048;

  f32x4 acc[2][4] = {};

  for (int kt = 0; kt < KD; kt += 64) {
#pragma unroll
    for (int c = 0; c < 2; ++c) {      // A: 2 chunks
      const int e = c * 2048 + tid * 8;
      const int row = (e >> 5) & 63, kc = e >> 11, o = e & 31;
      async_copy16(A + (size_t)(m0 + row) * KD + kt + kc * 32 + o, As + e);
    }
#pragma unroll
    for (int c = 0; c < 4; ++c) {      // B: 4 chunks
      const int e = c * 2048 + tid * 8;
      const int row = (e >> 5) & 127, kc = e >> 12, o = e & 31;
      async_copy16(B + (size_t)(n0 + row) * KD + kt + kc * 32 + o, Bs + e);
    }
    __syncthreads();
#pragma unroll
    for (int s = 0; s < 2; ++s) {
      bf16x8 af[2], bfr[4];
#pragma unroll
      for (int i = 0; i < 2; ++i)
        af[i] = *(const bf16x8*)(As + s * 2048 + (wm + i * 16 + l15) * 32 + l4 * 8);
#pragma unroll
      for (int j = 0; j < 4; ++j)
        bfr[j] = *(const bf16x8*)(Bs + s * 4096 + (wn + j * 16 + l15) * 32 + l4 * 8);
#pragma unroll
      for (int i = 0; i < 2; ++i)
#pragma unroll
        for (int j = 0; j < 4; ++j)
          acc[i][j] = __builtin_amdgcn_mfma_f32_16x16x32_bf16(af[i], bfr[j], acc[i][j], 0, 0, 0);
    }
    __syncthreads();
  }

  if (n0 < 2560) {  // Q or K: rope in-register
    const bool isQ = (n0 < 2048);
#pragma unroll
    for (int i = 0; i < 2; ++i)
#pragma unroll
      for (int j = 0; j < 4; ++j) {
        const int col = n0 + wn + j * 16 + l15;
        const int hd = isQ ? col : (col - 2048);
        const int hh = hd >> 6, d = hd & 63;
        const int fi = d & 31;
        const float ifr = __expf((float)fi * -0.41007385554f);  // theta^(-fi/32)
#pragma unroll
        for (int r = 0; r < 4; ++r) {
          const int m = m0 + wm + i * 16 + l4 * 4 + r;
          const int b = m >> 10, s = m & 1023;
          const float ang = (float)pos[m] * ifr;
          float sn, cs;
          __sincosf(ang, &sn, &cs);
          const float x  = acc[i][j][r];
          const float xp = acc[i][j ^ 2][r];   // partner (col^32)
          const float v = (d < 32) ? (x * cs - xp * sn) : (x * cs + xp * sn);
          if (isQ) Q[(((size_t)(b * 32 + hh)) * 1024 + s) * 64 + d] = (bf16)(v * 0.125f);
          else     K[(((size_t)(b * 8 + hh)) * 1024 + s) * 64 + d] = (bf16)v;
        }
      }
  } else {          // V: transpose to [B,NKV,64,S]
#pragma unroll
    for (int i = 0; i < 2; ++i)
#pragma unroll
      for (int j = 0; j < 4; ++j) {
        const int cv = n0 + wn + j * 16 + l15 - 2560;
        const int hh = cv >> 6, d = cv & 63;
#pragma unroll
        for (int r = 0; r < 4; ++r) {
          const int m = m0 + wm + i * 16 + l4 * 4 + r;
          const int b = m >> 10, s = m & 1023;
          V[(((size_t)(b * 8 + hh)) * 64 + d) * 1024 + s] = (bf16)acc[i][j][r];
        }
      }
  }
}

// ---------------------------------------------------------------------------
// Flash attention (unchanged numerics from round 6) + per-row sum-of-squares
// accumulation into ssum[] for the fused RMSNorm.
// ---------------------------------------------------------------------------
__global__ __launch_bounds__(256) void attn_kernel(
    const bf16* __restrict__ Q, const bf16* __restrict__ K,
    const bf16* __restrict__ Vt, bf16* __restrict__ O, float* __restrict__ ssum)
{
  __shared__ __align__(16) bf16 Ks[2 * 128 * 32];   // 16KB [dchunk][key][32]
  __shared__ __align__(16) bf16 Vs[4 * 64 * 32];    // 16KB [kchunk][d][32]
  __shared__ __align__(16) bf16 Ps[4 * 128 * 40];   // 40KB [kchunk][q][40]; Q-stage reuse

  const int tid = threadIdx.x, wave = tid >> 6, lane = tid & 63;
  const int l15 = lane & 15, l4 = lane >> 4;
  const int ip = blockIdx.x, bh = blockIdx.y;
  const int b = bh >> 5, h = bh & 31, kvh = h >> 2;
  const int qlo = ip * 64, qhi = (15 - ip) * 64;
  const bf16* Qb = Q + ((size_t)(b * 32 + h)) * 65536;
  const bf16* Kb = K + ((size_t)(b * 8 + kvh)) * 65536;
  const bf16* Vb = Vt + ((size_t)(b * 8 + kvh)) * 65536;

#pragma unroll
  for (int c = 0; c < 4; ++c) {
    const int e = c * 2048 + tid * 8;
    const int dchunk = e >> 12;
    const int row = (e & 4095) >> 5;
    const int qb = (row < 64) ? qlo : qhi;
    async_copy16(Qb + (size_t)(qb + (row & 63)) * 64 + dchunk * 32 + (e & 31), Ps + e);
  }
  __syncthreads();
  bf16x8 aq[2][2];   // [half][dchunk]
#pragma unroll
  for (int i = 0; i < 2; ++i)
#pragma unroll
    for (int s = 0; s < 2; ++s)
      aq[i][s] = *(const bf16x8*)(Ps + s * 4096 + (i * 64 + wave * 16 + l15) * 32 + l4 * 8);
  __syncthreads();

  float m_s[2][4], l_s[2][4];
  f32x4 o_acc[2][4] = {};
#pragma unroll
  for (int i = 0; i < 2; ++i)
#pragma unroll
    for (int r = 0; r < 4; ++r) { m_s[i][r] = -3.0e4f; l_s[i][r] = 0.f; }

  const int nkt = (1151 - 64 * ip) >> 7;
  for (int kt = 0; kt < nkt; ++kt) {
    const int k0 = kt * 128;
    const bool lo_act = (k0 < (ip + 1) * 64);
#pragma unroll
    for (int c = 0; c < 4; ++c) {
      const int e = c * 2048 + tid * 8;
      const int dchunk = e >> 12;
      const int krow = (e & 4095) >> 5;
      async_copy16(Kb + (size_t)(k0 + krow) * 64 + dchunk * 32 + (e & 31), Ks + e);
      const int kc = e >> 11;
      const int drow = (e & 2047) >> 5;
      async_copy16(Vb + (size_t)drow * 1024 + k0 + kc * 32 + (e & 31), Vs + e);
    }
    __syncthreads();

    f32x4 sc[2][8] = {};
#pragma unroll
    for (int j = 0; j < 8; ++j) {
      const bf16x8 bk0 = *(const bf16x8*)(Ks + (j * 16 + l15) * 32 + l4 * 8);
      const bf16x8 bk1 = *(const bf16x8*)(Ks + 4096 + (j * 16 + l15) * 32 + l4 * 8);
      sc[1][j] = __builtin_amdgcn_mfma_f32_16x16x32_bf16(aq[1][0], bk0, sc[1][j], 0, 0, 0);
      sc[1][j] = __builtin_amdgcn_mfma_f32_16x16x32_bf16(aq[1][1], bk1, sc[1][j], 0, 0, 0);
      if (lo_act) {
        sc[0][j] = __builtin_amdgcn_mfma_f32_16x16x32_bf16(aq[0][0], bk0, sc[0][j], 0, 0, 0);
        sc[0][j] = __builtin_amdgcn_mfma_f32_16x16x32_bf16(aq[0][1], bk1, sc[0][j], 0, 0, 0);
      }
    }

#pragma unroll
    for (int hh = 0; hh < 2; ++hh) {
      if (hh == 0 && !lo_act) continue;
      const int qb = hh ? qhi : qlo;
#pragma unroll
      for (int r = 0; r < 4; ++r) {
        const int rl = wave * 16 + l4 * 4 + r;
        const int rg = qb + rl;
        float mx = -3.0e4f;
#pragma unroll
        for (int j = 0; j < 8; ++j) {
          float v = sc[hh][j][r];
          if (k0 + j * 16 + l15 > rg) v = -3.0e4f;
          sc[hh][j][r] = v;
          mx = fmaxf(mx, v);
        }
#pragma unroll
        for (int off = 1; off < 16; off <<= 1) mx = fmaxf(mx, __shfl_xor(mx, off));
        const float mnew = fmaxf(m_s[hh][r], mx);
        const float alpha = __expf(m_s[hh][r] - mnew);
        m_s[hh][r] = mnew;
        float rs = 0.f;
#pragma unroll
        for (int j = 0; j < 8; ++j) {
          const float pv = __expf(sc[hh][j][r] - mnew);
          rs += pv;
          Ps[(j >> 1) * 5120 + (hh * 64 + rl) * 40 + (j & 1) * 16 + l15] = (bf16)pv;
        }
#pragma unroll
        for (int off = 1; off < 16; off <<= 1) rs += __shfl_xor(rs, off);
        l_s[hh][r] = l_s[hh][r] * alpha + rs;
#pragma unroll
        for (int jd = 0; jd < 4; ++jd) o_acc[hh][jd][r] *= alpha;
      }
    }
    __syncthreads();

#pragma unroll
    for (int ks = 0; ks < 4; ++ks) {
      bf16x8 bv[4];
#pragma unroll
      for (int jd = 0; jd < 4; ++jd)
        bv[jd] = *(const bf16x8*)(Vs + ks * 2048 + (jd * 16 + l15) * 32 + l4 * 8);
#pragma unroll
      for (int hh = 0; hh < 2; ++hh) {
        if (hh == 0 && !lo_act) continue;
        const bf16x8 ap = *(const bf16x8*)(Ps + ks * 5120 + (hh * 64 + wave * 16 + l15) * 40 + l4 * 8);
#pragma unroll
        for (int jd = 0; jd < 4; ++jd)
          o_acc[hh][jd] = __builtin_amdgcn_mfma_f32_16x16x32_bf16(ap, bv[jd], o_acc[hh][jd], 0, 0, 0);
      }
    }
    __syncthreads();
  }

  // ---- epilogue: O /= l, write [B*S, NH*64]; accumulate row sum-of-squares
#pragma unroll
  for (int hh = 0; hh < 2; ++hh) {
    const int qb = hh ? qhi : qlo;
#pragma unroll
    for (int r = 0; r < 4; ++r) {
      const float inv = 1.0f / l_s[hh][r];
      const int srow = qb + wave * 16 + l4 * 4 + r;
      bf16* op = O + ((size_t)(b * 1024 + srow)) * 2048 + h * 64;
      float ss = 0.f;
#pragma unroll
      for (int jd = 0; jd < 4; ++jd) {
        const float v = o_acc[hh][jd][r] * inv;
        op[jd * 16 + l15] = (bf16)v;
        ss += v * v;
      }
#pragma unroll
      for (int off = 1; off < 16; off <<= 1) ss += __shfl_xor(ss, off);
      if (l15 == 0) atomicAdd(&ssum[b * 1024 + srow], ss);
    }
  }
}

// ---------------------------------------------------------------------------
// rinv[m] = rsqrt(mean(ssum)/2048 + eps)
// ---------------------------------------------------------------------------
__global__ __launch_bounds__(256) void rsqrt_rows(
    const float* __restrict__ ssum, float* __restrict__ rinv) {
  const int i = blockIdx.x * 256 + threadIdx.x;
  if (i < 2048) rinv[i] = rsqrtf(ssum[i] * (1.0f / 2048.0f) + 1e-5f);
}

// ---------------------------------------------------------------------------
// GEMM2: out = rinv[m] * (attn_o x w_o'^T), dtype-steered write. BK=64.
// ---------------------------------------------------------------------------
__global__ __launch_bounds__(256) void gemm_out(
    const bf16* __restrict__ A, const bf16* __restrict__ B,
    const float* __restrict__ rinv,
    void* __restrict__ out, const int* __restrict__ flag)
{
  __shared__ __align__(16) bf16 As[2 * 64 * 32];
  __shared__ __align__(16) bf16 Bs[2 * 128 * 32];
  const int tid = threadIdx.x, wave = tid >> 6, lane = tid & 63;
  const int l15 = lane & 15, l4 = lane >> 4;
  const int m0 = blockIdx.y * 64, n0 = blockIdx.x * 128;
  const int wm = (wave >> 1) * 32, wn = (wave & 1) * 64;
  const int KD = 2048;

  f32x4 acc[2][4] = {};

  for (int kt = 0; kt < KD; kt += 64) {
#pragma unroll
    for (int c = 0; c < 2; ++c) {
      const int e = c * 2048 + tid * 8;
      const int row = (e >> 5) & 63, kc = e >> 11, o = e & 31;
      async_copy16(A + (size_t)(m0 + row) * KD + kt + kc * 32 + o, As + e);
    }
#pragma unroll
    for (int c = 0; c < 4; ++c) {
      const int e = c * 2048 + tid * 8;
      const int row = (e >> 5) & 127, kc = e >> 12, o = e & 31;
      async_copy16(B + (size_t)(n0 + row) * KD + kt + kc * 32 + o, Bs + e);
    }
    __syncthreads();
#pragma unroll
    for (int s = 0; s < 2; ++s) {
      bf16x8 af[2], bfr[4];
#pragma unroll
      for (int i = 0; i < 2; ++i)
        af[i] = *(const bf16x8*)(As + s * 2048 + (wm + i * 16 + l15) * 32 + l4 * 8);
#pragma unroll
      for (int j = 0; j < 4; ++j)
        bfr[j] = *(const bf16x8*)(Bs + s * 4096 + (wn + j * 16 + l15) * 32 + l4 * 8);
#pragma unroll
      for (int i = 0; i < 2; ++i)
#pragma unroll
        for (int j = 0; j < 4; ++j)
          acc[i][j] = __builtin_amdgcn_mfma_f32_16x16x32_bf16(af[i], bfr[j], acc[i][j], 0, 0, 0);
    }
    __syncthreads();
  }

  const bool f32out = (*flag != 0);
#pragma unroll
  for (int i = 0; i < 2; ++i)
#pragma unroll
    for (int r = 0; r < 4; ++r) {
      const int row = m0 + wm + i * 16 + l4 * 4 + r;
      const float ri = rinv[row];
#pragma unroll
      for (int j = 0; j < 4; ++j) {
        const int col = n0 + wn + j * 16 + l15;
        const size_t idx = (size_t)row * 2048 + col;
        const float v = ri * acc[i][j][r];
        if (f32out) ((float*)out)[idx] = v;
        else        ((bf16*)out)[idx]  = (bf16)v;
      }
    }
}

// ---------------------------------------------------------------------------
extern "C" void kernel_launch(void* const* d_in, const int* in_sizes, int n_in,
                              void* d_out, int out_size, void* d_ws, size_t ws_size,
                              hipStream_t stream) {
  const void* hs     = d_in[0];                // [2,1024,2048]  fp32 (or bf16)
  const int*  pos    = (const int*)d_in[1];    // [2,1024] int32
  const void* w_qkv  = d_in[2];                // [3072,2048]
  const void* w_o    = d_in[3];                // [2048,2048]
  const void* norm_w = d_in[4];                // [2048]

  char* ws = (char*)d_ws;
  bf16*  hs_b   = (bf16*) (ws);                   //  8,388,608
  bf16*  wqkv_b = (bf16*) (ws + 8388608);         // 12,582,912
  bf16*  w_o_b  = (bf16*) (ws + 20971520);        //  8,388,608 (norm_w folded)
  int*   flag   = (int*)  (ws + 29360128);        //         64
  float* ssum   = (float*)(ws + 29360192);        //      8,192
  bf16*  Qr     = (bf16*) (ws + 29368384);        //  8,388,608
  bf16*  Kr     = (bf16*) (ws + 37756992);        //  2,097,152
  bf16*  Vtr    = (bf16*) (ws + 39854144);        //  2,097,152
  bf16*  attn_o = (bf16*) (ws + 41951296);        //  8,388,608
  float* rinv   = (float*)(ws + 50339904);        //      8,192 (ends 50.35 MB)

  detect_dtype<<<1, 256, 0, stream>>>((const unsigned int*)hs, flag, ssum);
  convert_all<<<14336, 256, 0, stream>>>(hs, w_qkv, w_o, norm_w,
                                         hs_b, wqkv_b, w_o_b, flag);

  gemm_qkv_rope<<<dim3(24, 32), 256, 0, stream>>>(hs_b, wqkv_b, pos, Qr, Kr, Vtr);
  attn_kernel<<<dim3(8, 64), 256, 0, stream>>>(Qr, Kr, Vtr, attn_o, ssum);
  rsqrt_rows<<<8, 256, 0, stream>>>(ssum, rinv);
  gemm_out<<<dim3(16, 32), 256, 0, stream>>>(attn_o, w_o_b, rinv, d_out, flag);
}

// Round 8
// 212.957 us; speedup vs baseline: 1.4830x; 1.0007x over previous
//
#include <hip/hip_runtime.h>
#include <hip/hip_bf16.h>
#include <cstdint>
#include <cstddef>

typedef __bf16 bf16;
typedef __bf16 bf16x4 __attribute__((ext_vector_type(4)));
typedef __bf16 bf16x8 __attribute__((ext_vector_type(8)));
typedef float  f32x4  __attribute__((ext_vector_type(4)));

// async global->LDS, 16B per lane. LDS dest = wave-uniform base + lane*16B.
__device__ __forceinline__ void async_copy16(const void* g, void* l) {
  __builtin_amdgcn_global_load_lds((const __attribute__((address_space(1))) void*)g,
                                   (__attribute__((address_space(3))) void*)l,
                                   16, 0, 0);
}

// Per-block dtype flag from hs[0..127] words: fp32 mantissa-garbage decoded as
// bf16 has exponent >= 134 ~50% of the time; real bf16 N(0,1) never does.
__device__ __forceinline__ bool block_flag_is_f32(const unsigned int* w, int tid,
                                                  int* sflag) {
  if (tid < 64) {
    int weird = 0;
#pragma unroll
    for (int c = 0; c < 2; ++c) {
      const unsigned int lo = w[c * 64 + tid] & 0xffffu;
      const unsigned int ex = (lo >> 7) & 0xffu;
      if (ex >= 134u) ++weird;
    }
    const unsigned long long m1 = __ballot(weird >= 1);
    const unsigned long long m2 = __ballot(weird == 2);
    if (tid == 0) *sflag = (__popcll(m1) + __popcll(m2) >= 8) ? 1 : 0;
  }
  __syncthreads();
  return *sflag != 0;
}

// ---------------------------------------------------------------------------
// Fused convert (float4-unit indexed), flag computed per-block, block 0 also
// zero-inits ssum[2048].
//   [0, 1048576)           hs
//   [1048576, 2621440)     w_qkv
//   [2621440, 3670016)     w_o  (x norm_w[k] folded in)
// ---------------------------------------------------------------------------
__global__ __launch_bounds__(256) void convert_all(
    const void* __restrict__ s0, const void* __restrict__ s1,
    const void* __restrict__ s2, const void* __restrict__ s3,
    bf16* __restrict__ d0, bf16* __restrict__ d1, bf16* __restrict__ d2,
    float* __restrict__ ssum) {
  __shared__ int sflag;
  const int tid = threadIdx.x;
  const bool f32 = block_flag_is_f32((const unsigned int*)s0, tid, &sflag);
  if (blockIdx.x == 0) {
    ((float4*)ssum)[tid * 2]     = make_float4(0.f, 0.f, 0.f, 0.f);
    ((float4*)ssum)[tid * 2 + 1] = make_float4(0.f, 0.f, 0.f, 0.f);
  }
  const int i = blockIdx.x * 256 + tid;
  if (i >= 3670016) return;
  const void* src; bf16* dst; int off; bool fold = false;
  if      (i < 1048576) { src = s0; dst = d0; off = i; }
  else if (i < 2621440) { src = s1; dst = d1; off = i - 1048576; }
  else                  { src = s2; dst = d2; off = i - 2621440; fold = true; }
  float v[4];
  if (f32) {
    const float4 t = ((const float4*)src)[off];
    v[0] = t.x; v[1] = t.y; v[2] = t.z; v[3] = t.w;
  } else {
    const bf16x4 t = ((const bf16x4*)src)[off];
#pragma unroll
    for (int j = 0; j < 4; ++j) v[j] = (float)t[j];
  }
  if (fold) {
    const int k0 = (off * 4) & 2047;
#pragma unroll
    for (int j = 0; j < 4; ++j) {
      const float w = f32 ? ((const float*)s3)[k0 + j] : (float)((const bf16*)s3)[k0 + j];
      v[j] *= w;
    }
  }
  bf16x4 o;
#pragma unroll
  for (int j = 0; j < 4; ++j) o[j] = (bf16)v[j];
  *(bf16x4*)(dst + (size_t)off * 4) = o;
}

// ---------------------------------------------------------------------------
// GEMM1 + fused neox RoPE epilogue. Tile 64x128, BK=128 (4 k-steps/barrier).
// LDS 48KB -> 3 blocks/CU; grid 768 = 3/CU exact.
// ---------------------------------------------------------------------------
__global__ __launch_bounds__(256) void gemm_qkv_rope(
    const bf16* __restrict__ A, const bf16* __restrict__ B,
    const int* __restrict__ pos,
    bf16* __restrict__ Q, bf16* __restrict__ K, bf16* __restrict__ V)
{
  __shared__ __align__(16) bf16 As[4 * 64 * 32];    // 16KB [kc][row][32]
  __shared__ __align__(16) bf16 Bs[4 * 128 * 32];   // 32KB [kc][row][32]
  const int tid = threadIdx.x, wave = tid >> 6, lane = tid & 63;
  const int l15 = lane & 15, l4 = lane >> 4;
  const int m0 = blockIdx.y * 64, n0 = blockIdx.x * 128;
  const int wm = (wave >> 1) * 32, wn = (wave & 1) * 64;
  const int KD = 2048;

  f32x4 acc[2][4] = {};

  for (int kt = 0; kt < KD; kt += 128) {
#pragma unroll
    for (int c = 0; c < 4; ++c) {      // A: 4 chunks of 64x32
      const int e = c * 2048 + tid * 8;
      const int kc = e >> 11, row = (e >> 5) & 63, o = e & 31;
      async_copy16(A + (size_t)(m0 + row) * KD + kt + kc * 32 + o, As + e);
    }
#pragma unroll
    for (int c = 0; c < 8; ++c) {      // B: 8 chunks -> 4 kc of 128x32
      const int e = c * 2048 + tid * 8;
      const int kc = e >> 12, row = (e >> 5) & 127, o = e & 31;
      async_copy16(B + (size_t)(n0 + row) * KD + kt + kc * 32 + o, Bs + e);
    }
    __syncthreads();
#pragma unroll
    for (int s = 0; s < 4; ++s) {
      bf16x8 af[2], bfr[4];
#pragma unroll
      for (int i = 0; i < 2; ++i)
        af[i] = *(const bf16x8*)(As + s * 2048 + (wm + i * 16 + l15) * 32 + l4 * 8);
#pragma unroll
      for (int j = 0; j < 4; ++j)
        bfr[j] = *(const bf16x8*)(Bs + s * 4096 + (wn + j * 16 + l15) * 32 + l4 * 8);
#pragma unroll
      for (int i = 0; i < 2; ++i)
#pragma unroll
        for (int j = 0; j < 4; ++j)
          acc[i][j] = __builtin_amdgcn_mfma_f32_16x16x32_bf16(af[i], bfr[j], acc[i][j], 0, 0, 0);
    }
    __syncthreads();
  }

  if (n0 < 2560) {  // Q or K: rope in-register
    const bool isQ = (n0 < 2048);
#pragma unroll
    for (int i = 0; i < 2; ++i)
#pragma unroll
      for (int j = 0; j < 4; ++j) {
        const int col = n0 + wn + j * 16 + l15;
        const int hd = isQ ? col : (col - 2048);
        const int hh = hd >> 6, d = hd & 63;
        const int fi = d & 31;
        const float ifr = __expf((float)fi * -0.41007385554f);  // theta^(-fi/32)
#pragma unroll
        for (int r = 0; r < 4; ++r) {
          const int m = m0 + wm + i * 16 + l4 * 4 + r;
          const int b = m >> 10, s = m & 1023;
          const float ang = (float)pos[m] * ifr;
          float sn, cs;
          __sincosf(ang, &sn, &cs);
          const float x  = acc[i][j][r];
          const float xp = acc[i][j ^ 2][r];   // partner (col^32)
          const float v = (d < 32) ? (x * cs - xp * sn) : (x * cs + xp * sn);
          if (isQ) Q[(((size_t)(b * 32 + hh)) * 1024 + s) * 64 + d] = (bf16)(v * 0.125f);
          else     K[(((size_t)(b * 8 + hh)) * 1024 + s) * 64 + d] = (bf16)v;
        }
      }
  } else {          // V: transpose to [B,NKV,64,S]
#pragma unroll
    for (int i = 0; i < 2; ++i)
#pragma unroll
      for (int j = 0; j < 4; ++j) {
        const int cv = n0 + wn + j * 16 + l15 - 2560;
        const int hh = cv >> 6, d = cv & 63;
#pragma unroll
        for (int r = 0; r < 4; ++r) {
          const int m = m0 + wm + i * 16 + l4 * 4 + r;
          const int b = m >> 10, s = m & 1023;
          V[(((size_t)(b * 8 + hh)) * 64 + d) * 1024 + s] = (bf16)acc[i][j][r];
        }
      }
  }
}

// ---------------------------------------------------------------------------
// Flash attention (round-6 numerics) + mask-skip on non-diagonal tiles
// (identical math: mask is a no-op when k0+127 <= qb).
// ---------------------------------------------------------------------------
__global__ __launch_bounds__(256) void attn_kernel(
    const bf16* __restrict__ Q, const bf16* __restrict__ K,
    const bf16* __restrict__ Vt, bf16* __restrict__ O, float* __restrict__ ssum)
{
  __shared__ __align__(16) bf16 Ks[2 * 128 * 32];   // 16KB [dchunk][key][32]
  __shared__ __align__(16) bf16 Vs[4 * 64 * 32];    // 16KB [kchunk][d][32]
  __shared__ __align__(16) bf16 Ps[4 * 128 * 40];   // 40KB [kchunk][q][40]; Q-stage reuse

  const int tid = threadIdx.x, wave = tid >> 6, lane = tid & 63;
  const int l15 = lane & 15, l4 = lane >> 4;
  const int ip = blockIdx.x, bh = blockIdx.y;
  const int b = bh >> 5, h = bh & 31, kvh = h >> 2;
  const int qlo = ip * 64, qhi = (15 - ip) * 64;
  const bf16* Qb = Q + ((size_t)(b * 32 + h)) * 65536;
  const bf16* Kb = K + ((size_t)(b * 8 + kvh)) * 65536;
  const bf16* Vb = Vt + ((size_t)(b * 8 + kvh)) * 65536;

#pragma unroll
  for (int c = 0; c < 4; ++c) {
    const int e = c * 2048 + tid * 8;
    const int dchunk = e >> 12;
    const int row = (e & 4095) >> 5;
    const int qb = (row < 64) ? qlo : qhi;
    async_copy16(Qb + (size_t)(qb + (row & 63)) * 64 + dchunk * 32 + (e & 31), Ps + e);
  }
  __syncthreads();
  bf16x8 aq[2][2];   // [half][dchunk]
#pragma unroll
  for (int i = 0; i < 2; ++i)
#pragma unroll
    for (int s = 0; s < 2; ++s)
      aq[i][s] = *(const bf16x8*)(Ps + s * 4096 + (i * 64 + wave * 16 + l15) * 32 + l4 * 8);
  __syncthreads();

  float m_s[2][4], l_s[2][4];
  f32x4 o_acc[2][4] = {};
#pragma unroll
  for (int i = 0; i < 2; ++i)
#pragma unroll
    for (int r = 0; r < 4; ++r) { m_s[i][r] = -3.0e4f; l_s[i][r] = 0.f; }

  const int nkt = (1151 - 64 * ip) >> 7;
  for (int kt = 0; kt < nkt; ++kt) {
    const int k0 = kt * 128;
    const bool lo_act = (k0 < (ip + 1) * 64);
#pragma unroll
    for (int c = 0; c < 4; ++c) {
      const int e = c * 2048 + tid * 8;
      const int dchunk = e >> 12;
      const int krow = (e & 4095) >> 5;
      async_copy16(Kb + (size_t)(k0 + krow) * 64 + dchunk * 32 + (e & 31), Ks + e);
      const int kc = e >> 11;
      const int drow = (e & 2047) >> 5;
      async_copy16(Vb + (size_t)drow * 1024 + k0 + kc * 32 + (e & 31), Vs + e);
    }
    __syncthreads();

    f32x4 sc[2][8] = {};
#pragma unroll
    for (int j = 0; j < 8; ++j) {
      const bf16x8 bk0 = *(const bf16x8*)(Ks + (j * 16 + l15) * 32 + l4 * 8);
      const bf16x8 bk1 = *(const bf16x8*)(Ks + 4096 + (j * 16 + l15) * 32 + l4 * 8);
      sc[1][j] = __builtin_amdgcn_mfma_f32_16x16x32_bf16(aq[1][0], bk0, sc[1][j], 0, 0, 0);
      sc[1][j] = __builtin_amdgcn_mfma_f32_16x16x32_bf16(aq[1][1], bk1, sc[1][j], 0, 0, 0);
      if (lo_act) {
        sc[0][j] = __builtin_amdgcn_mfma_f32_16x16x32_bf16(aq[0][0], bk0, sc[0][j], 0, 0, 0);
        sc[0][j] = __builtin_amdgcn_mfma_f32_16x16x32_bf16(aq[0][1], bk1, sc[0][j], 0, 0, 0);
      }
    }

#pragma unroll
    for (int hh = 0; hh < 2; ++hh) {
      if (hh == 0 && !lo_act) continue;
      const int qb = hh ? qhi : qlo;
      const bool needMask = (k0 + 127 > qb);   // any masked key in this tile?
#pragma unroll
      for (int r = 0; r < 4; ++r) {
        const int rl = wave * 16 + l4 * 4 + r;
        float mx = -3.0e4f;
        if (needMask) {
          const int rg = qb + rl;
#pragma unroll
          for (int j = 0; j < 8; ++j) {
            float v = sc[hh][j][r];
            if (k0 + j * 16 + l15 > rg) v = -3.0e4f;
            sc[hh][j][r] = v;
            mx = fmaxf(mx, v);
          }
        } else {
#pragma unroll
          for (int j = 0; j < 8; ++j) mx = fmaxf(mx, sc[hh][j][r]);
        }
#pragma unroll
        for (int off = 1; off < 16; off <<= 1) mx = fmaxf(mx, __shfl_xor(mx, off));
        const float mnew = fmaxf(m_s[hh][r], mx);
        const float alpha = __expf(m_s[hh][r] - mnew);
        m_s[hh][r] = mnew;
        float rs = 0.f;
#pragma unroll
        for (int j = 0; j < 8; ++j) {
          const float pv = __expf(sc[hh][j][r] - mnew);
          rs += pv;
          Ps[(j >> 1) * 5120 + (hh * 64 + rl) * 40 + (j & 1) * 16 + l15] = (bf16)pv;
        }
#pragma unroll
        for (int off = 1; off < 16; off <<= 1) rs += __shfl_xor(rs, off);
        l_s[hh][r] = l_s[hh][r] * alpha + rs;
#pragma unroll
        for (int jd = 0; jd < 4; ++jd) o_acc[hh][jd][r] *= alpha;
      }
    }
    __syncthreads();

#pragma unroll
    for (int ks = 0; ks < 4; ++ks) {
      bf16x8 bv[4];
#pragma unroll
      for (int jd = 0; jd < 4; ++jd)
        bv[jd] = *(const bf16x8*)(Vs + ks * 2048 + (jd * 16 + l15) * 32 + l4 * 8);
#pragma unroll
      for (int hh = 0; hh < 2; ++hh) {
        if (hh == 0 && !lo_act) continue;
        const bf16x8 ap = *(const bf16x8*)(Ps + ks * 5120 + (hh * 64 + wave * 16 + l15) * 40 + l4 * 8);
#pragma unroll
        for (int jd = 0; jd < 4; ++jd)
          o_acc[hh][jd] = __builtin_amdgcn_mfma_f32_16x16x32_bf16(ap, bv[jd], o_acc[hh][jd], 0, 0, 0);
      }
    }
    __syncthreads();
  }

  // ---- epilogue: O /= l, write [B*S, NH*64]; accumulate row sum-of-squares
#pragma unroll
  for (int hh = 0; hh < 2; ++hh) {
    const int qb = hh ? qhi : qlo;
#pragma unroll
    for (int r = 0; r < 4; ++r) {
      const float inv = 1.0f / l_s[hh][r];
      const int srow = qb + wave * 16 + l4 * 4 + r;
      bf16* op = O + ((size_t)(b * 1024 + srow)) * 2048 + h * 64;
      float ss = 0.f;
#pragma unroll
      for (int jd = 0; jd < 4; ++jd) {
        const float v = o_acc[hh][jd][r] * inv;
        op[jd * 16 + l15] = (bf16)v;
        ss += v * v;
      }
#pragma unroll
      for (int off = 1; off < 16; off <<= 1) ss += __shfl_xor(ss, off);
      if (l15 == 0) atomicAdd(&ssum[b * 1024 + srow], ss);
    }
  }
}

// ---------------------------------------------------------------------------
// GEMM2: out = rsqrt(mean(ssum)+eps)[m] * (attn_o x w_o'^T). BK=128.
// Flag computed inline from hs; rinv inline from ssum.
// ---------------------------------------------------------------------------
__global__ __launch_bounds__(256) void gemm_out(
    const bf16* __restrict__ A, const bf16* __restrict__ B,
    const float* __restrict__ ssum, const unsigned int* __restrict__ hs_raw,
    void* __restrict__ out)
{
  __shared__ __align__(16) bf16 As[4 * 64 * 32];    // 16KB
  __shared__ __align__(16) bf16 Bs[4 * 128 * 32];   // 32KB
  __shared__ int sflag;
  const int tid = threadIdx.x, wave = tid >> 6, lane = tid & 63;
  const bool f32out = block_flag_is_f32(hs_raw, tid, &sflag);
  const int l15 = lane & 15, l4 = lane >> 4;
  const int m0 = blockIdx.y * 64, n0 = blockIdx.x * 128;
  const int wm = (wave >> 1) * 32, wn = (wave & 1) * 64;
  const int KD = 2048;

  f32x4 acc[2][4] = {};

  for (int kt = 0; kt < KD; kt += 128) {
#pragma unroll
    for (int c = 0; c < 4; ++c) {
      const int e = c * 2048 + tid * 8;
      const int kc = e >> 11, row = (e >> 5) & 63, o = e & 31;
      async_copy16(A + (size_t)(m0 + row) * KD + kt + kc * 32 + o, As + e);
    }
#pragma unroll
    for (int c = 0; c < 8; ++c) {
      const int e = c * 2048 + tid * 8;
      const int kc = e >> 12, row = (e >> 5) & 127, o = e & 31;
      async_copy16(B + (size_t)(n0 + row) * KD + kt + kc * 32 + o, Bs + e);
    }
    __syncthreads();
#pragma unroll
    for (int s = 0; s < 4; ++s) {
      bf16x8 af[2], bfr[4];
#pragma unroll
      for (int i = 0; i < 2; ++i)
        af[i] = *(const bf16x8*)(As + s * 2048 + (wm + i * 16 + l15) * 32 + l4 * 8);
#pragma unroll
      for (int j = 0; j < 4; ++j)
        bfr[j] = *(const bf16x8*)(Bs + s * 4096 + (wn + j * 16 + l15) * 32 + l4 * 8);
#pragma unroll
      for (int i = 0; i < 2; ++i)
#pragma unroll
        for (int j = 0; j < 4; ++j)
          acc[i][j] = __builtin_amdgcn_mfma_f32_16x16x32_bf16(af[i], bfr[j], acc[i][j], 0, 0, 0);
    }
    __syncthreads();
  }

#pragma unroll
  for (int i = 0; i < 2; ++i)
#pragma unroll
    for (int r = 0; r < 4; ++r) {
      const int row = m0 + wm + i * 16 + l4 * 4 + r;
      const float ri = rsqrtf(ssum[row] * (1.0f / 2048.0f) + 1e-5f);
#pragma unroll
      for (int j = 0; j < 4; ++j) {
        const int col = n0 + wn + j * 16 + l15;
        const size_t idx = (size_t)row * 2048 + col;
        const float v = ri * acc[i][j][r];
        if (f32out) ((float*)out)[idx] = v;
        else        ((bf16*)out)[idx]  = (bf16)v;
      }
    }
}

// ---------------------------------------------------------------------------
extern "C" void kernel_launch(void* const* d_in, const int* in_sizes, int n_in,
                              void* d_out, int out_size, void* d_ws, size_t ws_size,
                              hipStream_t stream) {
  const void* hs     = d_in[0];                // [2,1024,2048]  fp32 (or bf16)
  const int*  pos    = (const int*)d_in[1];    // [2,1024] int32
  const void* w_qkv  = d_in[2];                // [3072,2048]
  const void* w_o    = d_in[3];                // [2048,2048]
  const void* norm_w = d_in[4];                // [2048]

  char* ws = (char*)d_ws;
  bf16*  hs_b   = (bf16*) (ws);                   //  8,388,608
  bf16*  wqkv_b = (bf16*) (ws + 8388608);         // 12,582,912
  bf16*  w_o_b  = (bf16*) (ws + 20971520);        //  8,388,608 (norm_w folded)
  float* ssum   = (float*)(ws + 29360128);        //      8,192
  bf16*  Qr     = (bf16*) (ws + 29368320);        //  8,388,608
  bf16*  Kr     = (bf16*) (ws + 37756928);        //  2,097,152
  bf16*  Vtr    = (bf16*) (ws + 39854080);        //  2,097,152
  bf16*  attn_o = (bf16*) (ws + 41951232);        //  8,388,608 (ends ~50.3 MB)

  convert_all<<<14336, 256, 0, stream>>>(hs, w_qkv, w_o, norm_w,
                                         hs_b, wqkv_b, w_o_b, ssum);
  gemm_qkv_rope<<<dim3(24, 32), 256, 0, stream>>>(hs_b, wqkv_b, pos, Qr, Kr, Vtr);
  attn_kernel<<<dim3(8, 64), 256, 0, stream>>>(Qr, Kr, Vtr, attn_o, ssum);
  gemm_out<<<dim3(16, 32), 256, 0, stream>>>(attn_o, w_o_b, ssum,
                                             (const unsigned int*)hs, d_out);
}

// Round 9
// 207.098 us; speedup vs baseline: 1.5249x; 1.0283x over previous
//
#include <hip/hip_runtime.h>
#include <hip/hip_bf16.h>
#include <cstdint>
#include <cstddef>

typedef __bf16 bf16;
typedef __bf16 bf16x2 __attribute__((ext_vector_type(2)));
typedef __bf16 bf16x4 __attribute__((ext_vector_type(4)));
typedef __bf16 bf16x8 __attribute__((ext_vector_type(8)));
typedef float  f32x4  __attribute__((ext_vector_type(4)));

// async global->LDS, 16B per lane. LDS dest = wave-uniform base + lane*16B.
__device__ __forceinline__ void async_copy16(const void* g, void* l) {
  __builtin_amdgcn_global_load_lds((const __attribute__((address_space(1))) void*)g,
                                   (__attribute__((address_space(3))) void*)l,
                                   16, 0, 0);
}

// Per-block dtype flag from hs[0..127] words: fp32 mantissa-garbage decoded as
// bf16 has exponent >= 134 ~50% of the time; real bf16 N(0,1) never does.
__device__ __forceinline__ bool block_flag_is_f32(const unsigned int* w, int tid,
                                                  int* sflag) {
  if (tid < 64) {
    int weird = 0;
#pragma unroll
    for (int c = 0; c < 2; ++c) {
      const unsigned int lo = w[c * 64 + tid] & 0xffffu;
      const unsigned int ex = (lo >> 7) & 0xffu;
      if (ex >= 134u) ++weird;
    }
    const unsigned long long m1 = __ballot(weird >= 1);
    const unsigned long long m2 = __ballot(weird == 2);
    if (tid == 0) *sflag = (__popcll(m1) + __popcll(m2) >= 8) ? 1 : 0;
  }
  __syncthreads();
  return *sflag != 0;
}

// ---------------------------------------------------------------------------
// Fused convert (float4-unit indexed), flag computed per-block, block 0 also
// zero-inits ssum[2048].
// ---------------------------------------------------------------------------
__global__ __launch_bounds__(256) void convert_all(
    const void* __restrict__ s0, const void* __restrict__ s1,
    const void* __restrict__ s2, const void* __restrict__ s3,
    bf16* __restrict__ d0, bf16* __restrict__ d1, bf16* __restrict__ d2,
    float* __restrict__ ssum) {
  __shared__ int sflag;
  const int tid = threadIdx.x;
  const bool f32 = block_flag_is_f32((const unsigned int*)s0, tid, &sflag);
  if (blockIdx.x == 0) {
    ((float4*)ssum)[tid * 2]     = make_float4(0.f, 0.f, 0.f, 0.f);
    ((float4*)ssum)[tid * 2 + 1] = make_float4(0.f, 0.f, 0.f, 0.f);
  }
  const int i = blockIdx.x * 256 + tid;
  if (i >= 3670016) return;
  const void* src; bf16* dst; int off; bool fold = false;
  if      (i < 1048576) { src = s0; dst = d0; off = i; }
  else if (i < 2621440) { src = s1; dst = d1; off = i - 1048576; }
  else                  { src = s2; dst = d2; off = i - 2621440; fold = true; }
  float v[4];
  if (f32) {
    const float4 t = ((const float4*)src)[off];
    v[0] = t.x; v[1] = t.y; v[2] = t.z; v[3] = t.w;
  } else {
    const bf16x4 t = ((const bf16x4*)src)[off];
#pragma unroll
    for (int j = 0; j < 4; ++j) v[j] = (float)t[j];
  }
  if (fold) {
    const int k0 = (off * 4) & 2047;
#pragma unroll
    for (int j = 0; j < 4; ++j) {
      const float w = f32 ? ((const float*)s3)[k0 + j] : (float)((const bf16*)s3)[k0 + j];
      v[j] *= w;
    }
  }
  bf16x4 o;
#pragma unroll
  for (int j = 0; j < 4; ++j) o[j] = (bf16)v[j];
  *(bf16x4*)(dst + (size_t)off * 4) = o;
}

// ---------------------------------------------------------------------------
// GEMM1 + fused neox RoPE epilogue. Tile 64x128, BK=128.
// V is written with seq permuted within 32-blocks: s' = (s&~31) + κ⁻¹(s&31),
// κ⁻¹(k) = (k&15)*2 + (k>>4), matching attention's packed-P key order.
// ---------------------------------------------------------------------------
__global__ __launch_bounds__(256) void gemm_qkv_rope(
    const bf16* __restrict__ A, const bf16* __restrict__ B,
    const int* __restrict__ pos,
    bf16* __restrict__ Q, bf16* __restrict__ K, bf16* __restrict__ V)
{
  __shared__ __align__(16) bf16 As[4 * 64 * 32];    // 16KB [kc][row][32]
  __shared__ __align__(16) bf16 Bs[4 * 128 * 32];   // 32KB [kc][row][32]
  const int tid = threadIdx.x, wave = tid >> 6, lane = tid & 63;
  const int l15 = lane & 15, l4 = lane >> 4;
  const int m0 = blockIdx.y * 64, n0 = blockIdx.x * 128;
  const int wm = (wave >> 1) * 32, wn = (wave & 1) * 64;
  const int KD = 2048;

  f32x4 acc[2][4] = {};

  for (int kt = 0; kt < KD; kt += 128) {
#pragma unroll
    for (int c = 0; c < 4; ++c) {      // A: 4 chunks of 64x32
      const int e = c * 2048 + tid * 8;
      const int kc = e >> 11, row = (e >> 5) & 63, o = e & 31;
      async_copy16(A + (size_t)(m0 + row) * KD + kt + kc * 32 + o, As + e);
    }
#pragma unroll
    for (int c = 0; c < 8; ++c) {      // B: 8 chunks -> 4 kc of 128x32
      const int e = c * 2048 + tid * 8;
      const int kc = e >> 12, row = (e >> 5) & 127, o = e & 31;
      async_copy16(B + (size_t)(n0 + row) * KD + kt + kc * 32 + o, Bs + e);
    }
    __syncthreads();
#pragma unroll
    for (int s = 0; s < 4; ++s) {
      bf16x8 af[2], bfr[4];
#pragma unroll
      for (int i = 0; i < 2; ++i)
        af[i] = *(const bf16x8*)(As + s * 2048 + (wm + i * 16 + l15) * 32 + l4 * 8);
#pragma unroll
      for (int j = 0; j < 4; ++j)
        bfr[j] = *(const bf16x8*)(Bs + s * 4096 + (wn + j * 16 + l15) * 32 + l4 * 8);
#pragma unroll
      for (int i = 0; i < 2; ++i)
#pragma unroll
        for (int j = 0; j < 4; ++j)
          acc[i][j] = __builtin_amdgcn_mfma_f32_16x16x32_bf16(af[i], bfr[j], acc[i][j], 0, 0, 0);
    }
    __syncthreads();
  }

  if (n0 < 2560) {  // Q or K: rope in-register
    const bool isQ = (n0 < 2048);
#pragma unroll
    for (int i = 0; i < 2; ++i)
#pragma unroll
      for (int j = 0; j < 4; ++j) {
        const int col = n0 + wn + j * 16 + l15;
        const int hd = isQ ? col : (col - 2048);
        const int hh = hd >> 6, d = hd & 63;
        const int fi = d & 31;
        const float ifr = __expf((float)fi * -0.41007385554f);  // theta^(-fi/32)
#pragma unroll
        for (int r = 0; r < 4; ++r) {
          const int m = m0 + wm + i * 16 + l4 * 4 + r;
          const int b = m >> 10, s = m & 1023;
          const float ang = (float)pos[m] * ifr;
          float sn, cs;
          __sincosf(ang, &sn, &cs);
          const float x  = acc[i][j][r];
          const float xp = acc[i][j ^ 2][r];   // partner (col^32)
          const float v = (d < 32) ? (x * cs - xp * sn) : (x * cs + xp * sn);
          if (isQ) Q[(((size_t)(b * 32 + hh)) * 1024 + s) * 64 + d] = (bf16)(v * 0.125f);
          else     K[(((size_t)(b * 8 + hh)) * 1024 + s) * 64 + d] = (bf16)v;
        }
      }
  } else {          // V: transpose to [B,NKV,64,S], seq permuted within 32
#pragma unroll
    for (int i = 0; i < 2; ++i)
#pragma unroll
      for (int j = 0; j < 4; ++j) {
        const int cv = n0 + wn + j * 16 + l15 - 2560;
        const int hh = cv >> 6, d = cv & 63;
#pragma unroll
        for (int r = 0; r < 4; ++r) {
          const int m = m0 + wm + i * 16 + l4 * 4 + r;
          const int b = m >> 10, s = m & 1023;
          const int sp = (s & ~31) + ((s & 15) * 2 + ((s >> 4) & 1));
          V[(((size_t)(b * 8 + hh)) * 64 + d) * 1024 + sp] = (bf16)acc[i][j][r];
        }
      }
  }
}

// ---------------------------------------------------------------------------
// Flash attention (round-6 numerics). 2 barriers/tile (softmax->PV sync
// removed: P rows are wave-local). P written as packed b32 in κ-permuted key
// order; V global layout permuted to match (dot product invariant).
// ---------------------------------------------------------------------------
__global__ __launch_bounds__(256) void attn_kernel(
    const bf16* __restrict__ Q, const bf16* __restrict__ K,
    const bf16* __restrict__ Vt, bf16* __restrict__ O, float* __restrict__ ssum)
{
  __shared__ __align__(16) bf16 Ks[2 * 128 * 32];   // 16KB [dchunk][key][32]
  __shared__ __align__(16) bf16 Vs[4 * 64 * 32];    // 16KB [kchunk][d][32]
  __shared__ __align__(16) bf16 Ps[4 * 128 * 40];   // 40KB [kchunk][q][40]; Q-stage reuse

  const int tid = threadIdx.x, wave = tid >> 6, lane = tid & 63;
  const int l15 = lane & 15, l4 = lane >> 4;
  const int ip = blockIdx.x, bh = blockIdx.y;
  const int b = bh >> 5, h = bh & 31, kvh = h >> 2;
  const int qlo = ip * 64, qhi = (15 - ip) * 64;
  const bf16* Qb = Q + ((size_t)(b * 32 + h)) * 65536;
  const bf16* Kb = K + ((size_t)(b * 8 + kvh)) * 65536;
  const bf16* Vb = Vt + ((size_t)(b * 8 + kvh)) * 65536;

#pragma unroll
  for (int c = 0; c < 4; ++c) {
    const int e = c * 2048 + tid * 8;
    const int dchunk = e >> 12;
    const int row = (e & 4095) >> 5;
    const int qb = (row < 64) ? qlo : qhi;
    async_copy16(Qb + (size_t)(qb + (row & 63)) * 64 + dchunk * 32 + (e & 31), Ps + e);
  }
  __syncthreads();
  bf16x8 aq[2][2];   // [half][dchunk]
#pragma unroll
  for (int i = 0; i < 2; ++i)
#pragma unroll
    for (int s = 0; s < 2; ++s)
      aq[i][s] = *(const bf16x8*)(Ps + s * 4096 + (i * 64 + wave * 16 + l15) * 32 + l4 * 8);
  __syncthreads();

  float m_s[2][4], l_s[2][4];
  f32x4 o_acc[2][4] = {};
#pragma unroll
  for (int i = 0; i < 2; ++i)
#pragma unroll
    for (int r = 0; r < 4; ++r) { m_s[i][r] = -3.0e4f; l_s[i][r] = 0.f; }

  const int nkt = (1151 - 64 * ip) >> 7;
  for (int kt = 0; kt < nkt; ++kt) {
    const int k0 = kt * 128;
    const bool lo_act = (k0 < (ip + 1) * 64);
#pragma unroll
    for (int c = 0; c < 4; ++c) {
      const int e = c * 2048 + tid * 8;
      const int dchunk = e >> 12;
      const int krow = (e & 4095) >> 5;
      async_copy16(Kb + (size_t)(k0 + krow) * 64 + dchunk * 32 + (e & 31), Ks + e);
      const int kc = e >> 11;
      const int drow = (e & 2047) >> 5;
      async_copy16(Vb + (size_t)drow * 1024 + k0 + kc * 32 + (e & 31), Vs + e);
    }
    __syncthreads();

    f32x4 sc[2][8] = {};
#pragma unroll
    for (int j = 0; j < 8; ++j) {
      const bf16x8 bk0 = *(const bf16x8*)(Ks + (j * 16 + l15) * 32 + l4 * 8);
      const bf16x8 bk1 = *(const bf16x8*)(Ks + 4096 + (j * 16 + l15) * 32 + l4 * 8);
      sc[1][j] = __builtin_amdgcn_mfma_f32_16x16x32_bf16(aq[1][0], bk0, sc[1][j], 0, 0, 0);
      sc[1][j] = __builtin_amdgcn_mfma_f32_16x16x32_bf16(aq[1][1], bk1, sc[1][j], 0, 0, 0);
      if (lo_act) {
        sc[0][j] = __builtin_amdgcn_mfma_f32_16x16x32_bf16(aq[0][0], bk0, sc[0][j], 0, 0, 0);
        sc[0][j] = __builtin_amdgcn_mfma_f32_16x16x32_bf16(aq[0][1], bk1, sc[0][j], 0, 0, 0);
      }
    }

#pragma unroll
    for (int hh = 0; hh < 2; ++hh) {
      if (hh == 0 && !lo_act) continue;
      const int qb = hh ? qhi : qlo;
#pragma unroll
      for (int r = 0; r < 4; ++r) {
        const int rl = wave * 16 + l4 * 4 + r;
        const int rg = qb + rl;
        float mx = -3.0e4f;
#pragma unroll
        for (int j = 0; j < 8; ++j) {
          float v = sc[hh][j][r];
          if (k0 + j * 16 + l15 > rg) v = -3.0e4f;
          sc[hh][j][r] = v;
          mx = fmaxf(mx, v);
        }
#pragma unroll
        for (int off = 1; off < 16; off <<= 1) mx = fmaxf(mx, __shfl_xor(mx, off));
        const float mnew = fmaxf(m_s[hh][r], mx);
        const float alpha = __expf(m_s[hh][r] - mnew);
        m_s[hh][r] = mnew;
        float rs = 0.f;
#pragma unroll
        for (int t = 0; t < 4; ++t) {
          const float pv0 = __expf(sc[hh][2 * t][r]     - mnew);
          const float pv1 = __expf(sc[hh][2 * t + 1][r] - mnew);
          rs += pv0 + pv1;
          bf16x2 pk; pk[0] = (bf16)pv0; pk[1] = (bf16)pv1;
          *(bf16x2*)(Ps + t * 5120 + (hh * 64 + rl) * 40 + l15 * 2) = pk;
        }
#pragma unroll
        for (int off = 1; off < 16; off <<= 1) rs += __shfl_xor(rs, off);
        l_s[hh][r] = l_s[hh][r] * alpha + rs;
#pragma unroll
        for (int jd = 0; jd < 4; ++jd) o_acc[hh][jd][r] *= alpha;
      }
    }
    // NOTE: no __syncthreads here — P rows are written and read by the same
    // wave (A-frag row = hh*64 + wave*16 + l15); LDS ops are wave-ordered.

#pragma unroll
    for (int ks = 0; ks < 4; ++ks) {
      bf16x8 bv[4];
#pragma unroll
      for (int jd = 0; jd < 4; ++jd)
        bv[jd] = *(const bf16x8*)(Vs + ks * 2048 + (jd * 16 + l15) * 32 + l4 * 8);
#pragma unroll
      for (int hh = 0; hh < 2; ++hh) {
        if (hh == 0 && !lo_act) continue;
        const bf16x8 ap = *(const bf16x8*)(Ps + ks * 5120 + (hh * 64 + wave * 16 + l15) * 40 + l4 * 8);
#pragma unroll
        for (int jd = 0; jd < 4; ++jd)
          o_acc[hh][jd] = __builtin_amdgcn_mfma_f32_16x16x32_bf16(ap, bv[jd], o_acc[hh][jd], 0, 0, 0);
      }
    }
    __syncthreads();
  }

  // ---- epilogue: O /= l, write [B*S, NH*64]; accumulate row sum-of-squares
#pragma unroll
  for (int hh = 0; hh < 2; ++hh) {
    const int qb = hh ? qhi : qlo;
#pragma unroll
    for (int r = 0; r < 4; ++r) {
      const float inv = 1.0f / l_s[hh][r];
      const int srow = qb + wave * 16 + l4 * 4 + r;
      bf16* op = O + ((size_t)(b * 1024 + srow)) * 2048 + h * 64;
      float ss = 0.f;
#pragma unroll
      for (int jd = 0; jd < 4; ++jd) {
        const float v = o_acc[hh][jd][r] * inv;
        op[jd * 16 + l15] = (bf16)v;
        ss += v * v;
      }
#pragma unroll
      for (int off = 1; off < 16; off <<= 1) ss += __shfl_xor(ss, off);
      if (l15 == 0) atomicAdd(&ssum[b * 1024 + srow], ss);
    }
  }
}

// ---------------------------------------------------------------------------
// GEMM2: out = rsqrt(mean(ssum)+eps)[m] * (attn_o x w_o'^T). BK=128.
// ---------------------------------------------------------------------------
__global__ __launch_bounds__(256) void gemm_out(
    const bf16* __restrict__ A, const bf16* __restrict__ B,
    const float* __restrict__ ssum, const unsigned int* __restrict__ hs_raw,
    void* __restrict__ out)
{
  __shared__ __align__(16) bf16 As[4 * 64 * 32];    // 16KB
  __shared__ __align__(16) bf16 Bs[4 * 128 * 32];   // 32KB
  __shared__ int sflag;
  const int tid = threadIdx.x, wave = tid >> 6, lane = tid & 63;
  const bool f32out = block_flag_is_f32(hs_raw, tid, &sflag);
  const int l15 = lane & 15, l4 = lane >> 4;
  const int m0 = blockIdx.y * 64, n0 = blockIdx.x * 128;
  const int wm = (wave >> 1) * 32, wn = (wave & 1) * 64;
  const int KD = 2048;

  f32x4 acc[2][4] = {};

  for (int kt = 0; kt < KD; kt += 128) {
#pragma unroll
    for (int c = 0; c < 4; ++c) {
      const int e = c * 2048 + tid * 8;
      const int kc = e >> 11, row = (e >> 5) & 63, o = e & 31;
      async_copy16(A + (size_t)(m0 + row) * KD + kt + kc * 32 + o, As + e);
    }
#pragma unroll
    for (int c = 0; c < 8; ++c) {
      const int e = c * 2048 + tid * 8;
      const int kc = e >> 12, row = (e >> 5) & 127, o = e & 31;
      async_copy16(B + (size_t)(n0 + row) * KD + kt + kc * 32 + o, Bs + e);
    }
    __syncthreads();
#pragma unroll
    for (int s = 0; s < 4; ++s) {
      bf16x8 af[2], bfr[4];
#pragma unroll
      for (int i = 0; i < 2; ++i)
        af[i] = *(const bf16x8*)(As + s * 2048 + (wm + i * 16 + l15) * 32 + l4 * 8);
#pragma unroll
      for (int j = 0; j < 4; ++j)
        bfr[j] = *(const bf16x8*)(Bs + s * 4096 + (wn + j * 16 + l15) * 32 + l4 * 8);
#pragma unroll
      for (int i = 0; i < 2; ++i)
#pragma unroll
        for (int j = 0; j < 4; ++j)
          acc[i][j] = __builtin_amdgcn_mfma_f32_16x16x32_bf16(af[i], bfr[j], acc[i][j], 0, 0, 0);
    }
    __syncthreads();
  }

#pragma unroll
  for (int i = 0; i < 2; ++i)
#pragma unroll
    for (int r = 0; r < 4; ++r) {
      const int row = m0 + wm + i * 16 + l4 * 4 + r;
      const float ri = rsqrtf(ssum[row] * (1.0f / 2048.0f) + 1e-5f);
#pragma unroll
      for (int j = 0; j < 4; ++j) {
        const int col = n0 + wn + j * 16 + l15;
        const size_t idx = (size_t)row * 2048 + col;
        const float v = ri * acc[i][j][r];
        if (f32out) ((float*)out)[idx] = v;
        else        ((bf16*)out)[idx]  = (bf16)v;
      }
    }
}

// ---------------------------------------------------------------------------
extern "C" void kernel_launch(void* const* d_in, const int* in_sizes, int n_in,
                              void* d_out, int out_size, void* d_ws, size_t ws_size,
                              hipStream_t stream) {
  const void* hs     = d_in[0];                // [2,1024,2048]  fp32 (or bf16)
  const int*  pos    = (const int*)d_in[1];    // [2,1024] int32
  const void* w_qkv  = d_in[2];                // [3072,2048]
  const void* w_o    = d_in[3];                // [2048,2048]
  const void* norm_w = d_in[4];                // [2048]

  char* ws = (char*)d_ws;
  bf16*  hs_b   = (bf16*) (ws);                   //  8,388,608
  bf16*  wqkv_b = (bf16*) (ws + 8388608);         // 12,582,912
  bf16*  w_o_b  = (bf16*) (ws + 20971520);        //  8,388,608 (norm_w folded)
  float* ssum   = (float*)(ws + 29360128);        //      8,192
  bf16*  Qr     = (bf16*) (ws + 29368320);        //  8,388,608
  bf16*  Kr     = (bf16*) (ws + 37756928);        //  2,097,152
  bf16*  Vtr    = (bf16*) (ws + 39854080);        //  2,097,152
  bf16*  attn_o = (bf16*) (ws + 41951232);        //  8,388,608 (ends ~50.3 MB)

  convert_all<<<14336, 256, 0, stream>>>(hs, w_qkv, w_o, norm_w,
                                         hs_b, wqkv_b, w_o_b, ssum);
  gemm_qkv_rope<<<dim3(24, 32), 256, 0, stream>>>(hs_b, wqkv_b, pos, Qr, Kr, Vtr);
  attn_kernel<<<dim3(8, 64), 256, 0, stream>>>(Qr, Kr, Vtr, attn_o, ssum);
  gemm_out<<<dim3(16, 32), 256, 0, stream>>>(attn_o, w_o_b, ssum,
                                             (const unsigned int*)hs, d_out);
}